// Round 11
// baseline (438.501 us; speedup 1.0000x reference)
//
#include <hip/hip_runtime.h>

// Problem constants
constexpr int NB  = 4;
constexpr int NH  = 12;
constexpr int SEQ = 1024;   // LQ == LK
constexpr int DKd = 64;
constexpr int DVd = 768;
constexpr int Ed  = 768;    // E == H*DK
constexpr int HVd = 9216;   // H*DV

typedef float f32x4 __attribute__((ext_vector_type(4)));
typedef short s16x8 __attribute__((ext_vector_type(8)));

__device__ __forceinline__ unsigned short f2bf(float f) {
  unsigned int u = __builtin_bit_cast(unsigned int, f);
  u += 0x7fffu + ((u >> 16) & 1u);          // RNE
  return (unsigned short)(u >> 16);
}
__device__ __forceinline__ float bf2f(unsigned short h) {
  return __builtin_bit_cast(float, (unsigned int)h << 16);
}
__device__ __forceinline__ float bf2f_lo(unsigned int u) {
  return __builtin_bit_cast(float, u << 16);
}
__device__ __forceinline__ float bf2f_hi(unsigned int u) {
  return __builtin_bit_cast(float, u & 0xffff0000u);
}
// argmax comparator: higher value wins; ties -> lower index (matches jnp.argmax)
__device__ __forceinline__ bool better(float va, int ia, float vb, int ib) {
  return va > vb || (va == vb && ia < ib);
}

__device__ __forceinline__ f32x4 mfma_bf16_16x16x32(s16x8 a, s16x8 b, f32x4 c) {
  asm("v_mfma_f32_16x16x32_bf16 %0, %1, %2, %0" : "+v"(c) : "v"(a), "v"(b));
  return c;
}

#define GLOAD16(g, l)                                                          \
  __builtin_amdgcn_global_load_lds(                                            \
      (const __attribute__((address_space(1))) unsigned int*)(g),              \
      (__attribute__((address_space(3))) unsigned int*)(l), 16, 0, 0)

// ---------------------------------------------------------------------------
// q,k (f32) -> hi/lo bf16 split (Markidis)   [R5-proven]
// ---------------------------------------------------------------------------
__global__ __launch_bounds__(256)
void split_qk_kernel(const float* __restrict__ q, const float* __restrict__ k,
                     unsigned short* __restrict__ Qhi, unsigned short* __restrict__ Qlo,
                     unsigned short* __restrict__ Khi, unsigned short* __restrict__ Klo,
                     int n4) {
  const float* src = blockIdx.z ? k : q;
  unsigned short* hi = blockIdx.z ? Khi : Qhi;
  unsigned short* lo = blockIdx.z ? Klo : Qlo;
  int i = blockIdx.x * 256 + threadIdx.x;
  const int stride = gridDim.x * 256;
  for (; i < n4; i += stride) {
    const f32x4 x = *(const f32x4*)&src[(size_t)i * 4];
    unsigned short h[4], l[4];
#pragma unroll
    for (int c = 0; c < 4; c++) {
      h[c] = f2bf(x[c]);
      l[c] = f2bf(x[c] - bf2f(h[c]));
    }
    uint2 uh, ul;
    uh.x = (unsigned)h[0] | ((unsigned)h[1] << 16);
    uh.y = (unsigned)h[2] | ((unsigned)h[3] << 16);
    ul.x = (unsigned)l[0] | ((unsigned)l[1] << 16);
    ul.y = (unsigned)l[2] | ((unsigned)l[3] << 16);
    *(uint2*)&hi[(size_t)i * 4] = uh;
    *(uint2*)&lo[(size_t)i * 4] = ul;
  }
}

// ---------------------------------------------------------------------------
// w (f32 [e][n]) -> WT hi/lo bf16 [n][e]  (transpose + split)   [R5-proven]
// ---------------------------------------------------------------------------
__global__ __launch_bounds__(256)
void split_wT_kernel(const float* __restrict__ w_qs, const float* __restrict__ w_ks,
                     unsigned short* __restrict__ WqThi, unsigned short* __restrict__ WqTlo,
                     unsigned short* __restrict__ WkThi, unsigned short* __restrict__ WkTlo) {
  __shared__ float Ts[64][68];
  const float* src = blockIdx.z ? w_ks : w_qs;
  unsigned short* hi = blockIdx.z ? WkThi : WqThi;
  unsigned short* lo = blockIdx.z ? WkTlo : WqTlo;
  const int e0 = blockIdx.x * 64, n0 = blockIdx.y * 64;
  const int tid = threadIdx.x;
  const int row = tid >> 2, cc = (tid & 3) * 16;
#pragma unroll
  for (int j = 0; j < 4; j++)
    *(f32x4*)&Ts[row][cc + 4 * j] = *(const f32x4*)&src[(size_t)(e0 + row) * 768 + n0 + cc + 4 * j];
  __syncthreads();
  const int r = tid >> 2, cs = (tid & 3) * 16;
  s16x8 ph[2], pl[2];
#pragma unroll
  for (int j = 0; j < 16; j++) {
    const float v = Ts[cs + j][r];
    const unsigned short h = f2bf(v);
    const unsigned short l = f2bf(v - bf2f(h));
    ph[j >> 3][j & 7] = (short)h;
    pl[j >> 3][j & 7] = (short)l;
  }
  const size_t ob = (size_t)(n0 + r) * 768 + e0 + cs;
  *(s16x8*)&hi[ob] = ph[0];
  *(s16x8*)&hi[ob + 8] = ph[1];
  *(s16x8*)&lo[ob] = pl[0];
  *(s16x8*)&lo[ob + 8] = pl[1];
}

// ---------------------------------------------------------------------------
// Projected heads = A @ W via 3-term bf16 MFMA; OUTPUT = bf16 hi/lo planes
// (same split arithmetic as split_qk).  Body = R5-proven text.
// ---------------------------------------------------------------------------
__global__ __launch_bounds__(256)
void qkproj_mfma_kernel(const unsigned short* __restrict__ Qhi, const unsigned short* __restrict__ Qlo,
                        const unsigned short* __restrict__ Khi, const unsigned short* __restrict__ Klo,
                        const unsigned short* __restrict__ WqThi, const unsigned short* __restrict__ WqTlo,
                        const unsigned short* __restrict__ WkThi, const unsigned short* __restrict__ WkTlo,
                        unsigned short* __restrict__ QHhi, unsigned short* __restrict__ QHlo,
                        unsigned short* __restrict__ KHhi, unsigned short* __restrict__ KHlo) {
  const unsigned short* Ahi = blockIdx.z ? Khi : Qhi;
  const unsigned short* Alo = blockIdx.z ? Klo : Qlo;
  const unsigned short* Bhi = blockIdx.z ? WkThi : WqThi;
  const unsigned short* Blo = blockIdx.z ? WkTlo : WqTlo;
  unsigned short* Chi = blockIdx.z ? KHhi : QHhi;
  unsigned short* Clo = blockIdx.z ? KHlo : QHlo;
  __shared__ unsigned short AhiS[128 * 64], AloS[128 * 64];
  __shared__ unsigned short BhiS[64 * 64], BloS[64 * 64];
  const int tid = threadIdx.x;
  const int wid = tid >> 6, lane = tid & 63;
  const int m0 = blockIdx.x * 128, n0 = blockIdx.y * 64;
  const int wr = (wid >> 1) * 64, wc = (wid & 1) * 32;
  const int lm = lane & 15, lq = lane >> 4;
  const int srow = wid * 8 + (lane >> 3);
  const int scols = (((lane & 7) * 16) ^ ((srow & 7) << 4)) >> 1;
  const int ldst = wid * 512;
  const int xs = (lm & 7) << 3;

  const unsigned short* ahi0 = Ahi + (size_t)(m0 + srow) * 768 + scols;
  const unsigned short* alo0 = Alo + (size_t)(m0 + srow) * 768 + scols;
  const unsigned short* bhi0 = Bhi + (size_t)(n0 + srow) * 768 + scols;
  const unsigned short* blo0 = Blo + (size_t)(n0 + srow) * 768 + scols;

  f32x4 acc[4][2];
#pragma unroll
  for (int m = 0; m < 4; m++)
#pragma unroll
    for (int n = 0; n < 2; n++)
#pragma unroll
      for (int r = 0; r < 4; r++) acc[m][n][r] = 0.f;

  for (int k0 = 0; k0 < 768; k0 += 64) {
#pragma unroll
    for (int j = 0; j < 4; j++) {
      GLOAD16(ahi0 + (size_t)j * 32 * 768 + k0, &AhiS[j * 2048 + ldst]);
      GLOAD16(alo0 + (size_t)j * 32 * 768 + k0, &AloS[j * 2048 + ldst]);
    }
#pragma unroll
    for (int j = 0; j < 2; j++) {
      GLOAD16(bhi0 + (size_t)j * 32 * 768 + k0, &BhiS[j * 2048 + ldst]);
      GLOAD16(blo0 + (size_t)j * 32 * 768 + k0, &BloS[j * 2048 + ldst]);
    }
    __syncthreads();
#pragma unroll
    for (int ks = 0; ks < 2; ks++) {
      const int kc = (ks * 32 + lq * 8) ^ xs;
      s16x8 ah[4], al[4], bh[2], bl[2];
#pragma unroll
      for (int m = 0; m < 4; m++) {
        ah[m] = *(const s16x8*)&AhiS[(wr + m * 16 + lm) * 64 + kc];
        al[m] = *(const s16x8*)&AloS[(wr + m * 16 + lm) * 64 + kc];
      }
#pragma unroll
      for (int n = 0; n < 2; n++) {
        bh[n] = *(const s16x8*)&BhiS[(wc + n * 16 + lm) * 64 + kc];
        bl[n] = *(const s16x8*)&BloS[(wc + n * 16 + lm) * 64 + kc];
      }
#pragma unroll
      for (int m = 0; m < 4; m++)
#pragma unroll
        for (int n = 0; n < 2; n++) {
          acc[m][n] = mfma_bf16_16x16x32(ah[m], bh[n], acc[m][n]);
          acc[m][n] = mfma_bf16_16x16x32(al[m], bh[n], acc[m][n]);
          acc[m][n] = mfma_bf16_16x16x32(ah[m], bl[n], acc[m][n]);
        }
    }
    __syncthreads();
  }
  asm volatile("s_nop 7\n\ts_nop 7");
#pragma unroll
  for (int m = 0; m < 4; m++)
#pragma unroll
    for (int n = 0; n < 2; n++)
#pragma unroll
      for (int r = 0; r < 4; r++) {
        const float vv = acc[m][n][r];
        const unsigned short hh = f2bf(vv);
        const unsigned short ll = f2bf(vv - bf2f(hh));
        const size_t off =
            (size_t)(m0 + wr + m * 16 + lq * 4 + r) * 768 + n0 + wc + n * 16 + lm;
        Chi[off] = hh;
        Clo[off] = ll;
      }
}

// ---------------------------------------------------------------------------
// Score v6: R10's LDS-free swapped-operand kernel, 3 heads/block (was 6) ->
// grid (8,8,16) = 1024 blocks = 4 blocks/CU = 2x the waves for latency hiding.
// ---------------------------------------------------------------------------
__global__ __launch_bounds__(256)
void score_mfma6_kernel(const unsigned short* __restrict__ QHhi, const unsigned short* __restrict__ QHlo,
                        const unsigned short* __restrict__ KHhi, const unsigned short* __restrict__ KHlo,
                        const float* __restrict__ qkm, const float* __restrict__ km,
                        const float* __restrict__ pm, float4* __restrict__ partials) {
  const int z = blockIdx.z, b = z >> 2, hseg = z & 3;
  const int q0 = blockIdx.y * 128, k0 = blockIdx.x * 128;
  const int tid = threadIdx.x;
  const int wid = tid >> 6, lane = tid & 63;
  const int wk = (wid >> 1) * 64, wq = (wid & 1) * 64;   // wave k/q offsets
  const int lm = lane & 15, lq = lane >> 4;

  // ---- masks -> registers, direct (no LDS bounce) ----
  f32x4 msr[4][4];   // [n(q)][m(k)] -> 4 k-consecutive values
  {
    f32x4 kmv[4];
#pragma unroll
    for (int m = 0; m < 4; m++)
      kmv[m] = *(const f32x4*)&km[b * SEQ + k0 + wk + m * 16 + lq * 4];
#pragma unroll
    for (int n = 0; n < 4; n++) {
      const size_t rowb = (size_t)(b * SEQ + q0 + wq + n * 16 + lm) * SEQ + k0 + wk;
#pragma unroll
      for (int m = 0; m < 4; m++) {
        const f32x4 qv = *(const f32x4*)&qkm[rowb + m * 16 + lq * 4];
        const f32x4 pv = *(const f32x4*)&pm[rowb + m * 16 + lq * 4];
        f32x4 o;
#pragma unroll
        for (int c = 0; c < 4; c++)
          o[c] = pv[c] > 0.f ? qv[c] + kmv[m][c] : -3.0e38f;
        msr[n][m] = o;
      }
    }
  }

  const size_t kbase = (size_t)(b * SEQ + k0 + wk + lm) * 768;
  const size_t qbase = (size_t)(b * SEQ + q0 + wq + lm) * 768;

  for (int hl = 0; hl < 3; hl++) {
    const int h = hseg * 3 + hl;
    const int bh = b * NH + h;
    const int hb = h * 64;

    f32x4 acc[4][4];   // [m(k-subtile)][n(q-subtile)]
#pragma unroll
    for (int m = 0; m < 4; m++)
#pragma unroll
      for (int n = 0; n < 4; n++)
#pragma unroll
        for (int r = 0; r < 4; r++) acc[m][n][r] = 0.f;

#pragma unroll
    for (int ks = 0; ks < 2; ks++) {
      const int kc = hb + ks * 32 + lq * 8;
      s16x8 khf[4], klf[4];
#pragma unroll
      for (int m = 0; m < 4; m++) {
        const size_t off = kbase + (size_t)(m * 16) * 768 + kc;
        khf[m] = *(const s16x8*)&KHhi[off];
        klf[m] = *(const s16x8*)&KHlo[off];
      }
#pragma unroll
      for (int n = 0; n < 4; n++) {
        const size_t off = qbase + (size_t)(n * 16) * 768 + kc;
        const s16x8 qhf = *(const s16x8*)&QHhi[off];
        const s16x8 qlf = *(const s16x8*)&QHlo[off];
#pragma unroll
        for (int m = 0; m < 4; m++) {
          acc[m][n] = mfma_bf16_16x16x32(khf[m], qhf, acc[m][n]);
          acc[m][n] = mfma_bf16_16x16x32(klf[m], qhf, acc[m][n]);
          acc[m][n] = mfma_bf16_16x16x32(khf[m], qlf, acc[m][n]);
        }
      }
    }
    asm volatile("s_nop 7\n\ts_nop 7");

    // epilogue: per lane, 4 q's (n) x 16 k-candidates in registers [R9-proven]
#pragma unroll
    for (int n = 0; n < 4; n++) {
      const int qg = q0 + wq + n * 16 + lm;
      float v1 = -3.0e38f, v2 = -3.0e38f;
      int i1 = 0, i2 = 0;
#pragma unroll
      for (int m = 0; m < 4; m++)
#pragma unroll
        for (int r = 0; r < 4; r++) {
          const int kg = k0 + wk + m * 16 + lq * 4 + r;
          const float s = acc[m][n][r] * 0.125f + msr[n][m][r];
          if (better(s, kg, v1, i1)) { v2 = v1; i2 = i1; v1 = s; i1 = kg; }
          else if (better(s, kg, v2, i2)) { v2 = s; i2 = kg; }
        }
      // reduce across the 4 lq groups sharing this q (xor 16, 32)
#pragma unroll
      for (int off = 16; off < 64; off <<= 1) {
        const float w1 = __shfl_xor(v1, off); const int j1 = __shfl_xor(i1, off);
        const float w2 = __shfl_xor(v2, off); const int j2 = __shfl_xor(i2, off);
        if (better(w1, j1, v1, i1)) {
          if (better(v1, i1, w2, j2)) { v2 = v1; i2 = i1; } else { v2 = w2; i2 = j2; }
          v1 = w1; i1 = j1;
        } else if (better(w1, j1, v2, i2)) { v2 = w1; i2 = j1; }
      }
      if (lq == 0)
        partials[(size_t)(bh * SEQ + qg) * 16 + blockIdx.x * 2 + (wid >> 1)] =
            make_float4(v1, __int_as_float(i1), v2, __int_as_float(i2));
    }
  }
}

__global__ __launch_bounds__(256)
void argmax_reduce_kernel(const float4* __restrict__ partials, int* __restrict__ kmaxp,
                          float4* __restrict__ aux) {
  const int t = blockIdx.x * 256 + threadIdx.x;
  if (t >= NB * NH * SEQ) return;
  const float4* p = partials + (size_t)t * 16;
  float v1 = -3.0e38f, v2 = -3.0e38f;
  int i1 = 0, i2 = 0;
#pragma unroll
  for (int i = 0; i < 16; i++) {
    const float w1 = p[i].x; const int j1 = __float_as_int(p[i].y);
    const float w2 = p[i].z; const int j2 = __float_as_int(p[i].w);
    if (better(w1, j1, v1, i1)) {
      if (better(v1, i1, w2, j2)) { v2 = v1; i2 = i1; } else { v2 = w2; i2 = j2; }
      v1 = w1; i1 = j1;
    } else if (better(w1, j1, v2, i2)) { v2 = w1; i2 = j1; }
  }
  kmaxp[t] = i1;
  aux[t] = make_float4(v1, __int_as_float(i1), v2, __int_as_float(i2));
}

// ---------------------------------------------------------------------------
// Rescue: rows with approx top-2 gap < 2e-3 get exact fp32 rescoring from
// raw q,k,w.  Makes argmax fp32-exact.
// ---------------------------------------------------------------------------
__global__ __launch_bounds__(256)
void rescue_kernel(const float4* __restrict__ aux, const float* __restrict__ q,
                   const float* __restrict__ k, const float* __restrict__ w_qs,
                   const float* __restrict__ w_ks, const float* __restrict__ qkm,
                   const float* __restrict__ km, const float* __restrict__ pm,
                   int* __restrict__ kmaxp) {
  const int row = blockIdx.x * 4 + (threadIdx.x >> 6);
  const float4 a = aux[row];
  if (a.x - a.z > 2e-3f) return;
  const int i1 = __float_as_int(a.y), i2 = __float_as_int(a.w);
  if (i1 == i2) return;
  const int bh = row >> 10, qq = row & 1023;
  const int b = bh / NH, h = bh % NH;
  const int lane = threadIdx.x & 63;
  const float* qr = q + (size_t)(b * SEQ + qq) * Ed;
  const float* k1 = k + (size_t)(b * SEQ + i1) * Ed;
  const float* k2 = k + (size_t)(b * SEQ + i2) * Ed;
  const float* wq = w_qs + h * DKd + lane;
  const float* wk = w_ks + h * DKd + lane;
  float qd = 0.f, k1d = 0.f, k2d = 0.f;
#pragma unroll 4
  for (int e = 0; e < Ed; e++) {
    const float wqe = wq[(size_t)e * 768];
    const float wke = wk[(size_t)e * 768];
    qd  += qr[e] * wqe;
    k1d += k1[e] * wke;
    k2d += k2[e] * wke;
  }
  float s1 = qd * k1d, s2 = qd * k2d;
#pragma unroll
  for (int off = 1; off < 64; off <<= 1) {
    s1 += __shfl_xor(s1, off);
    s2 += __shfl_xor(s2, off);
  }
  const size_t m1 = (size_t)(b * SEQ + qq) * SEQ + i1;
  const size_t m2 = (size_t)(b * SEQ + qq) * SEQ + i2;
  s1 = s1 * 0.125f + (pm[m1] > 0.f ? qkm[m1] + km[b * SEQ + i1] : -3.0e38f);
  s2 = s2 * 0.125f + (pm[m2] > 0.f ? qkm[m2] + km[b * SEQ + i2] : -3.0e38f);
  if (lane == 0) kmaxp[row] = better(s1, i1, s2, i2) ? i1 : i2;
}

// ---------------------------------------------------------------------------
// v (f32) -> Vbf (bf16)
// ---------------------------------------------------------------------------
__global__ __launch_bounds__(256)
void cvt_bf16_kernel(const float* __restrict__ v, unsigned short* __restrict__ Vbf, int n4) {
  int i = blockIdx.x * 256 + threadIdx.x;
  const int stride = gridDim.x * 256;
  for (; i < n4; i += stride) {
    const f32x4 x = *(const f32x4*)&v[(size_t)i * 4];
    uint2 u;
    u.x = (unsigned)f2bf(x[0]) | ((unsigned)f2bf(x[1]) << 16);
    u.y = (unsigned)f2bf(x[2]) | ((unsigned)f2bf(x[3]) << 16);
    *(uint2*)&Vbf[(size_t)i * 4] = u;
  }
}

// ---------------------------------------------------------------------------
// MstbT[h][n][k] = (w_vs[:,h*768:+768] @ fc[h*768:+768,:])^T  (bf16)
// ---------------------------------------------------------------------------
__global__ __launch_bounds__(256)
void wvfc_gemm_kernel(const float* __restrict__ wvs, const float* __restrict__ fcw,
                      unsigned short* __restrict__ MstbT) {
  __shared__ unsigned short As[128][72];
  __shared__ unsigned short Bs[128][72];
  const int tid = threadIdx.x;
  const int h = blockIdx.z;
  const int m0 = blockIdx.x * 128, n0 = blockIdx.y * 128;
  const int wid = tid >> 6, lane = tid & 63;
  const int wr = (wid >> 1) * 64, wc = (wid & 1) * 64;
  const int lm = lane & 15, lq = lane >> 4;
  const int ar = tid >> 1, acb = (tid & 1) * 32;
  const int br = tid >> 2, bnb = (tid & 3) * 32;

  f32x4 acc[4][4];
#pragma unroll
  for (int m = 0; m < 4; m++)
#pragma unroll
    for (int n = 0; n < 4; n++)
#pragma unroll
      for (int r = 0; r < 4; r++) acc[m][n][r] = 0.f;

  for (int k0 = 0; k0 < 768; k0 += 64) {
    const float* asrc = wvs + (size_t)(m0 + ar) * HVd + h * 768 + k0 + acb;
    const float* bsrc = fcw + (size_t)(h * 768 + k0 + br) * 768 + n0 + bnb;
    f32x4 a4[8], b4[8];
#pragma unroll
    for (int i = 0; i < 8; i++) a4[i] = *(const f32x4*)&asrc[4 * i];
#pragma unroll
    for (int i = 0; i < 8; i++) b4[i] = *(const f32x4*)&bsrc[4 * i];
    __syncthreads();
#pragma unroll
    for (int i = 0; i < 4; i++) {
      s16x8 pk;
#pragma unroll
      for (int j = 0; j < 8; j++) pk[j] = (short)f2bf(a4[2 * i + (j >> 2)][j & 3]);
      *(s16x8*)&As[ar][acb + 8 * i] = pk;
    }
#pragma unroll
    for (int i = 0; i < 8; i++)
#pragma unroll
      for (int c = 0; c < 4; c++) Bs[bnb + 4 * i + c][br] = f2bf(b4[i][c]);
    __syncthreads();
#pragma unroll
    for (int ks = 0; ks < 2; ks++) {
      s16x8 af[4], bfr[4];
#pragma unroll
      for (int m = 0; m < 4; m++)
        af[m] = *(const s16x8*)&As[wr + m * 16 + lm][ks * 32 + lq * 8];
#pragma unroll
      for (int n = 0; n < 4; n++)
        bfr[n] = *(const s16x8*)&Bs[wc + n * 16 + lm][ks * 32 + lq * 8];
#pragma unroll
      for (int m = 0; m < 4; m++)
#pragma unroll
        for (int n = 0; n < 4; n++)
          acc[m][n] = mfma_bf16_16x16x32(af[m], bfr[n], acc[m][n]);
    }
  }
  asm volatile("s_nop 7\n\ts_nop 7");
#pragma unroll
  for (int m = 0; m < 4; m++)
#pragma unroll
    for (int n = 0; n < 4; n++) {
      const int grow0 = m0 + wr + m * 16 + lq * 4;
      const int gcol  = n0 + wc + n * 16 + lm;
      uint2 u;
      u.x = (unsigned)f2bf(acc[m][n][0]) | ((unsigned)f2bf(acc[m][n][1]) << 16);
      u.y = (unsigned)f2bf(acc[m][n][2]) | ((unsigned)f2bf(acc[m][n][3]) << 16);
      *(uint2*)&MstbT[(size_t)(h * 768 + gcol) * 768 + grow0] = u;
    }
}

// ---------------------------------------------------------------------------
// U[hg][4096][768p] = Vbf[4096][768] @ M_{h0+hg}  (bf16, gload_lds) [R5-proven]
// ---------------------------------------------------------------------------
__global__ __launch_bounds__(256)
void ugemm_kernel(const unsigned short* __restrict__ Vbf,
                  const unsigned short* __restrict__ MstbT,
                  unsigned short* __restrict__ U, int h0) {
  __shared__ unsigned short As[128 * 64];
  __shared__ unsigned short Bs[128 * 64];
  const int tid = threadIdx.x;
  const int h = h0 + blockIdx.z;
  const int bx = (int)blockIdx.x;
  const int sx = ((bx & 7) << 2) | (bx >> 3);
  const int m0 = sx * 128, n0 = blockIdx.y * 128;
  const int wid = tid >> 6, lane = tid & 63;
  const int wr = (wid >> 1) * 64, wc = (wid & 1) * 64;
  const int lm = lane & 15, lq = lane >> 4;
  const int srow = tid >> 3, scol = (tid & 7) * 8;
  const int ldst = (tid >> 6) * 512;

  const unsigned short* asrc = Vbf + (size_t)(m0 + srow) * 768 + scol;
  const unsigned short* bsrc = MstbT + (size_t)(h * 768 + n0 + srow) * 768 + scol;

  f32x4 acc[4][4];
#pragma unroll
  for (int m = 0; m < 4; m++)
#pragma unroll
    for (int n = 0; n < 4; n++)
#pragma unroll
      for (int r = 0; r < 4; r++) acc[m][n][r] = 0.f;

  for (int k0 = 0; k0 < 768; k0 += 64) {
#pragma unroll
    for (int j = 0; j < 4; j++)
      GLOAD16(asrc + (size_t)j * 32 * 768 + k0, &As[j * 2048 + ldst]);
#pragma unroll
    for (int j = 0; j < 4; j++)
      GLOAD16(bsrc + (size_t)j * 32 * 768 + k0, &Bs[j * 2048 + ldst]);
    __syncthreads();
#pragma unroll
    for (int ks = 0; ks < 2; ks++) {
      s16x8 af[4], bfr[4];
#pragma unroll
      for (int m = 0; m < 4; m++)
        af[m] = *(const s16x8*)&As[(wr + m * 16 + lm) * 64 + ks * 32 + lq * 8];
#pragma unroll
      for (int n = 0; n < 4; n++)
        bfr[n] = *(const s16x8*)&Bs[(wc + n * 16 + lm) * 64 + ks * 32 + lq * 8];
#pragma unroll
      for (int m = 0; m < 4; m++)
#pragma unroll
        for (int n = 0; n < 4; n++)
          acc[m][n] = mfma_bf16_16x16x32(af[m], bfr[n], acc[m][n]);
    }
    __syncthreads();
  }
  asm volatile("s_nop 7\n\ts_nop 7");
  const size_t urow0 = (size_t)blockIdx.z * 4096;
#pragma unroll
  for (int m = 0; m < 4; m++)
#pragma unroll
    for (int r = 0; r < 4; r++) {
      const int row = m0 + wr + m * 16 + lq * 4 + r;
      uint2 u;
      u.x = (unsigned)f2bf(acc[m][0][r]) | ((unsigned)f2bf(acc[m][1][r]) << 16);
      u.y = (unsigned)f2bf(acc[m][2][r]) | ((unsigned)f2bf(acc[m][3][r]) << 16);
      *(uint2*)&U[(urow0 + row) * 768 + n0 + wc + lm * 4] = u;
    }
}

// ---------------------------------------------------------------------------
// out0[row,:] (+)= sum_hg U[hg][kmax][:]  (+ v residual when h0==0)
// ---------------------------------------------------------------------------
__global__ __launch_bounds__(192)
void gathersum_kernel(const unsigned short* __restrict__ U, const int* __restrict__ kmaxp,
                      const float* __restrict__ v, float* __restrict__ out0,
                      int h0, int nhg) {
  const int row = blockIdx.x;
  const int b = row >> 10, q = row & 1023;
  const int t = threadIdx.x;
  float a0 = 0.f, a1 = 0.f, a2 = 0.f, a3 = 0.f;
  for (int hg = 0; hg < nhg; hg++) {
    const int g = kmaxp[((b * NH + h0 + hg) << 10) + q];
    const uint2 u = *(const uint2*)&U[((size_t)hg * 4096 + (b << 10) + g) * 768 + t * 4];
    a0 += bf2f_lo(u.x);
    a1 += bf2f_hi(u.x);
    a2 += bf2f_lo(u.y);
    a3 += bf2f_hi(u.y);
  }
  const int chunk = t >> 4, lmm = t & 15;
  const size_t ob = (size_t)row * 768 + chunk * 64 + lmm;
  if (h0 == 0) {
    out0[ob +  0] = a0 + v[ob +  0];
    out0[ob + 16] = a1 + v[ob + 16];
    out0[ob + 32] = a2 + v[ob + 32];
    out0[ob + 48] = a3 + v[ob + 48];
  } else {
    out0[ob +  0] += a0;
    out0[ob + 16] += a1;
    out0[ob + 32] += a2;
    out0[ob + 48] += a3;
  }
}

// ---------------------------------------------------------------------------
// attn = one-hot(kmax)
// ---------------------------------------------------------------------------
__global__ void onehot_kernel(const int* __restrict__ kmaxp, f32x4* __restrict__ attn, int n4) {
  int i = blockIdx.x * blockDim.x + threadIdx.x;
  const int stride = gridDim.x * blockDim.x;
  for (; i < n4; i += stride) {
    const int row = i >> 8;
    const int c0 = (i & 255) * 4;
    const int km = kmaxp[row];
    f32x4 o;
#pragma unroll
    for (int c = 0; c < 4; c++) o[c] = (c0 + c == km) ? 1.0f : 0.0f;
    attn[i] = o;
  }
}

// ---------------------------------------------------------------------------
extern "C" void kernel_launch(void* const* d_in, const int* in_sizes, int n_in,
                              void* d_out, int out_size, void* d_ws, size_t ws_size,
                              hipStream_t stream) {
  (void)in_sizes; (void)n_in; (void)out_size; (void)ws_size;
  const float* q       = (const float*)d_in[0];
  const float* k       = (const float*)d_in[1];
  const float* v       = (const float*)d_in[2];
  const float* qk_mask = (const float*)d_in[5];
  const float* k_mask  = (const float*)d_in[6];
  const float* pmask   = (const float*)d_in[7];
  const float* w_qs    = (const float*)d_in[8];
  const float* w_ks    = (const float*)d_in[9];
  const float* w_vs    = (const float*)d_in[10];
  const float* fc      = (const float*)d_in[11];

  float* out0 = (float*)d_out;
  float* attn = out0 + (size_t)NB * SEQ * DVd;

  // workspace (<= 58.4 MB extent, same as R5-R10), phase overlaps:
  // p1: rawQ/K splits@0..25.2M | W splits@25.2..29.9M |
  //     QHhi@33.23M QHlo@39.52M KHhi@45.81M KHlo@52.10M (ends 58.39M)
  //     partials@0 (raw splits dead after proj), aux@12.58M (raw Khi, dead)
  // p2: MstbT@0, Vbf@14.16M, U@20.45M..58.2M
  // kmaxp@58.2M (tail of KHlo range; KHlo dead before kmaxp written)
  char* ws = (char*)d_ws;
  unsigned short* Qhi   = (unsigned short*)ws;
  unsigned short* Qlo   = (unsigned short*)(ws + 6291456);
  unsigned short* Khi   = (unsigned short*)(ws + 12582912);
  unsigned short* Klo   = (unsigned short*)(ws + 18874368);
  unsigned short* WqThi = (unsigned short*)(ws + 25165824);
  unsigned short* WqTlo = (unsigned short*)(ws + 26345472);
  unsigned short* WkThi = (unsigned short*)(ws + 27525120);
  unsigned short* WkTlo = (unsigned short*)(ws + 28704768);
  unsigned short* QHhi  = (unsigned short*)(ws + 33226752);
  unsigned short* QHlo  = (unsigned short*)(ws + 39518208);
  unsigned short* KHhi  = (unsigned short*)(ws + 45809664);
  unsigned short* KHlo  = (unsigned short*)(ws + 52101120);
  float4* partials      = (float4*)ws;                       // 12,582,912 B
  float4* aux           = (float4*)(ws + 12582912);          //    786,432 B
  unsigned short* MstbT = (unsigned short*)ws;               // 14,155,776 B
  unsigned short* Vbf   = (unsigned short*)(ws + 14155776);  //  6,291,456 B
  unsigned short* U     = (unsigned short*)(ws + 20447232);  // 37,748,736 B
  int* kmaxp            = (int*)(ws + 58195968);             //    196,608 B

  // 1) bf16 hi/lo splits of raw q,k and transposed splits of w_qs,w_ks
  split_qk_kernel<<<dim3(1536, 1, 2), 256, 0, stream>>>(q, k, Qhi, Qlo, Khi, Klo,
                                                        NB * SEQ * Ed / 4);
  split_wT_kernel<<<dim3(12, 12, 2), 256, 0, stream>>>(w_qs, w_ks, WqThi, WqTlo,
                                                       WkThi, WkTlo);

  // 2) projections on matrix pipe -> bf16 hi/lo planes
  qkproj_mfma_kernel<<<dim3(32, 12, 2), 256, 0, stream>>>(
      Qhi, Qlo, Khi, Klo, WqThi, WqTlo, WkThi, WkTlo, QHhi, QHlo, KHhi, KHlo);

  // 3) scores on matrix pipe, LDS-free, 3 heads/block (4 blocks/CU)
  score_mfma6_kernel<<<dim3(8, 8, NB * 4), 256, 0, stream>>>(
      QHhi, QHlo, KHhi, KHlo, qk_mask, k_mask, pmask, partials);
  argmax_reduce_kernel<<<dim3(192), 256, 0, stream>>>(partials, kmaxp, aux);

  // 4) exact fp32 rescoring of near-ties (gap < 2e-3)
  rescue_kernel<<<dim3(12288), 256, 0, stream>>>(aux, q, k, w_qs, w_ks,
                                                 qk_mask, k_mask, pmask, kmaxp);

  // 5) v -> bf16 ; per-head M^T (bf16)
  cvt_bf16_kernel<<<dim3(3072), 256, 0, stream>>>(v, Vbf, NB * SEQ * DVd / 4);
  wvfc_gemm_kernel<<<dim3(6, 6, NH), 256, 0, stream>>>(w_vs, fc, MstbT);

  // 6) dense U_h = Vbf @ M_h, then gather+sum into out0  (two 6-head passes)
  ugemm_kernel<<<dim3(32, 6, 6), 256, 0, stream>>>(Vbf, MstbT, U, 0);
  gathersum_kernel<<<dim3(NB * SEQ), 192, 0, stream>>>(U, kmaxp, v, out0, 0, 6);
  ugemm_kernel<<<dim3(32, 6, 6), 256, 0, stream>>>(Vbf, MstbT, U, 6);
  gathersum_kernel<<<dim3(NB * SEQ), 192, 0, stream>>>(U, kmaxp, v, out0, 6, 6);

  // 7) attn = one-hot(kmax)
  onehot_kernel<<<dim3(2048), 256, 0, stream>>>(kmaxp, (f32x4*)attn,
                                                (int)((size_t)NB * NH * SEQ * SEQ / 4));
}

// Round 12
// 416.493 us; speedup vs baseline: 1.0528x; 1.0528x over previous
//
#include <hip/hip_runtime.h>

// Problem constants
constexpr int NB  = 4;
constexpr int NH  = 12;
constexpr int SEQ = 1024;   // LQ == LK
constexpr int DKd = 64;
constexpr int DVd = 768;
constexpr int Ed  = 768;    // E == H*DK
constexpr int HVd = 9216;   // H*DV

typedef float f32x4 __attribute__((ext_vector_type(4)));
typedef short s16x8 __attribute__((ext_vector_type(8)));

__device__ __forceinline__ unsigned short f2bf(float f) {
  unsigned int u = __builtin_bit_cast(unsigned int, f);
  u += 0x7fffu + ((u >> 16) & 1u);          // RNE
  return (unsigned short)(u >> 16);
}
__device__ __forceinline__ float bf2f(unsigned short h) {
  return __builtin_bit_cast(float, (unsigned int)h << 16);
}
__device__ __forceinline__ float bf2f_lo(unsigned int u) {
  return __builtin_bit_cast(float, u << 16);
}
__device__ __forceinline__ float bf2f_hi(unsigned int u) {
  return __builtin_bit_cast(float, u & 0xffff0000u);
}
// argmax comparator: higher value wins; ties -> lower index (matches jnp.argmax)
__device__ __forceinline__ bool better(float va, int ia, float vb, int ib) {
  return va > vb || (va == vb && ia < ib);
}

__device__ __forceinline__ f32x4 mfma_bf16_16x16x32(s16x8 a, s16x8 b, f32x4 c) {
  asm("v_mfma_f32_16x16x32_bf16 %0, %1, %2, %0" : "+v"(c) : "v"(a), "v"(b));
  return c;
}

#define GLOAD16(g, l)                                                          \
  __builtin_amdgcn_global_load_lds(                                            \
      (const __attribute__((address_space(1))) unsigned int*)(g),              \
      (__attribute__((address_space(3))) unsigned int*)(l), 16, 0, 0)

// ---------------------------------------------------------------------------
// q,k (f32) -> hi/lo bf16 split (Markidis)   [R5-proven]
// ---------------------------------------------------------------------------
__global__ __launch_bounds__(256)
void split_qk_kernel(const float* __restrict__ q, const float* __restrict__ k,
                     unsigned short* __restrict__ Qhi, unsigned short* __restrict__ Qlo,
                     unsigned short* __restrict__ Khi, unsigned short* __restrict__ Klo,
                     int n4) {
  const float* src = blockIdx.z ? k : q;
  unsigned short* hi = blockIdx.z ? Khi : Qhi;
  unsigned short* lo = blockIdx.z ? Klo : Qlo;
  int i = blockIdx.x * 256 + threadIdx.x;
  const int stride = gridDim.x * 256;
  for (; i < n4; i += stride) {
    const f32x4 x = *(const f32x4*)&src[(size_t)i * 4];
    unsigned short h[4], l[4];
#pragma unroll
    for (int c = 0; c < 4; c++) {
      h[c] = f2bf(x[c]);
      l[c] = f2bf(x[c] - bf2f(h[c]));
    }
    uint2 uh, ul;
    uh.x = (unsigned)h[0] | ((unsigned)h[1] << 16);
    uh.y = (unsigned)h[2] | ((unsigned)h[3] << 16);
    ul.x = (unsigned)l[0] | ((unsigned)l[1] << 16);
    ul.y = (unsigned)l[2] | ((unsigned)l[3] << 16);
    *(uint2*)&hi[(size_t)i * 4] = uh;
    *(uint2*)&lo[(size_t)i * 4] = ul;
  }
}

// ---------------------------------------------------------------------------
// w (f32 [e][n]) -> WT hi/lo bf16 [n][e]  (transpose + split)   [R5-proven]
// ---------------------------------------------------------------------------
__global__ __launch_bounds__(256)
void split_wT_kernel(const float* __restrict__ w_qs, const float* __restrict__ w_ks,
                     unsigned short* __restrict__ WqThi, unsigned short* __restrict__ WqTlo,
                     unsigned short* __restrict__ WkThi, unsigned short* __restrict__ WkTlo) {
  __shared__ float Ts[64][68];
  const float* src = blockIdx.z ? w_ks : w_qs;
  unsigned short* hi = blockIdx.z ? WkThi : WqThi;
  unsigned short* lo = blockIdx.z ? WkTlo : WqTlo;
  const int e0 = blockIdx.x * 64, n0 = blockIdx.y * 64;
  const int tid = threadIdx.x;
  const int row = tid >> 2, cc = (tid & 3) * 16;
#pragma unroll
  for (int j = 0; j < 4; j++)
    *(f32x4*)&Ts[row][cc + 4 * j] = *(const f32x4*)&src[(size_t)(e0 + row) * 768 + n0 + cc + 4 * j];
  __syncthreads();
  const int r = tid >> 2, cs = (tid & 3) * 16;
  s16x8 ph[2], pl[2];
#pragma unroll
  for (int j = 0; j < 16; j++) {
    const float v = Ts[cs + j][r];
    const unsigned short h = f2bf(v);
    const unsigned short l = f2bf(v - bf2f(h));
    ph[j >> 3][j & 7] = (short)h;
    pl[j >> 3][j & 7] = (short)l;
  }
  const size_t ob = (size_t)(n0 + r) * 768 + e0 + cs;
  *(s16x8*)&hi[ob] = ph[0];
  *(s16x8*)&hi[ob + 8] = ph[1];
  *(s16x8*)&lo[ob] = pl[0];
  *(s16x8*)&lo[ob + 8] = pl[1];
}

// ---------------------------------------------------------------------------
// Projected heads = A @ W via 3-term bf16 MFMA; OUTPUT = bf16 hi/lo planes
// (same split arithmetic as split_qk).  Body = R5-proven text.
// ---------------------------------------------------------------------------
__global__ __launch_bounds__(256)
void qkproj_mfma_kernel(const unsigned short* __restrict__ Qhi, const unsigned short* __restrict__ Qlo,
                        const unsigned short* __restrict__ Khi, const unsigned short* __restrict__ Klo,
                        const unsigned short* __restrict__ WqThi, const unsigned short* __restrict__ WqTlo,
                        const unsigned short* __restrict__ WkThi, const unsigned short* __restrict__ WkTlo,
                        unsigned short* __restrict__ QHhi, unsigned short* __restrict__ QHlo,
                        unsigned short* __restrict__ KHhi, unsigned short* __restrict__ KHlo) {
  const unsigned short* Ahi = blockIdx.z ? Khi : Qhi;
  const unsigned short* Alo = blockIdx.z ? Klo : Qlo;
  const unsigned short* Bhi = blockIdx.z ? WkThi : WqThi;
  const unsigned short* Blo = blockIdx.z ? WkTlo : WqTlo;
  unsigned short* Chi = blockIdx.z ? KHhi : QHhi;
  unsigned short* Clo = blockIdx.z ? KHlo : QHlo;
  __shared__ unsigned short AhiS[128 * 64], AloS[128 * 64];
  __shared__ unsigned short BhiS[64 * 64], BloS[64 * 64];
  const int tid = threadIdx.x;
  const int wid = tid >> 6, lane = tid & 63;
  const int m0 = blockIdx.x * 128, n0 = blockIdx.y * 64;
  const int wr = (wid >> 1) * 64, wc = (wid & 1) * 32;
  const int lm = lane & 15, lq = lane >> 4;
  const int srow = wid * 8 + (lane >> 3);
  const int scols = (((lane & 7) * 16) ^ ((srow & 7) << 4)) >> 1;
  const int ldst = wid * 512;
  const int xs = (lm & 7) << 3;

  const unsigned short* ahi0 = Ahi + (size_t)(m0 + srow) * 768 + scols;
  const unsigned short* alo0 = Alo + (size_t)(m0 + srow) * 768 + scols;
  const unsigned short* bhi0 = Bhi + (size_t)(n0 + srow) * 768 + scols;
  const unsigned short* blo0 = Blo + (size_t)(n0 + srow) * 768 + scols;

  f32x4 acc[4][2];
#pragma unroll
  for (int m = 0; m < 4; m++)
#pragma unroll
    for (int n = 0; n < 2; n++)
#pragma unroll
      for (int r = 0; r < 4; r++) acc[m][n][r] = 0.f;

  for (int k0 = 0; k0 < 768; k0 += 64) {
#pragma unroll
    for (int j = 0; j < 4; j++) {
      GLOAD16(ahi0 + (size_t)j * 32 * 768 + k0, &AhiS[j * 2048 + ldst]);
      GLOAD16(alo0 + (size_t)j * 32 * 768 + k0, &AloS[j * 2048 + ldst]);
    }
#pragma unroll
    for (int j = 0; j < 2; j++) {
      GLOAD16(bhi0 + (size_t)j * 32 * 768 + k0, &BhiS[j * 2048 + ldst]);
      GLOAD16(blo0 + (size_t)j * 32 * 768 + k0, &BloS[j * 2048 + ldst]);
    }
    __syncthreads();
#pragma unroll
    for (int ks = 0; ks < 2; ks++) {
      const int kc = (ks * 32 + lq * 8) ^ xs;
      s16x8 ah[4], al[4], bh[2], bl[2];
#pragma unroll
      for (int m = 0; m < 4; m++) {
        ah[m] = *(const s16x8*)&AhiS[(wr + m * 16 + lm) * 64 + kc];
        al[m] = *(const s16x8*)&AloS[(wr + m * 16 + lm) * 64 + kc];
      }
#pragma unroll
      for (int n = 0; n < 2; n++) {
        bh[n] = *(const s16x8*)&BhiS[(wc + n * 16 + lm) * 64 + kc];
        bl[n] = *(const s16x8*)&BloS[(wc + n * 16 + lm) * 64 + kc];
      }
#pragma unroll
      for (int m = 0; m < 4; m++)
#pragma unroll
        for (int n = 0; n < 2; n++) {
          acc[m][n] = mfma_bf16_16x16x32(ah[m], bh[n], acc[m][n]);
          acc[m][n] = mfma_bf16_16x16x32(al[m], bh[n], acc[m][n]);
          acc[m][n] = mfma_bf16_16x16x32(ah[m], bl[n], acc[m][n]);
        }
    }
    __syncthreads();
  }
  asm volatile("s_nop 7\n\ts_nop 7");
#pragma unroll
  for (int m = 0; m < 4; m++)
#pragma unroll
    for (int n = 0; n < 2; n++)
#pragma unroll
      for (int r = 0; r < 4; r++) {
        const float vv = acc[m][n][r];
        const unsigned short hh = f2bf(vv);
        const unsigned short ll = f2bf(vv - bf2f(hh));
        const size_t off =
            (size_t)(m0 + wr + m * 16 + lq * 4 + r) * 768 + n0 + wc + n * 16 + lm;
        Chi[off] = hh;
        Clo[off] = ll;
      }
}

// ---------------------------------------------------------------------------
// Score v5 [R10-proven]: ZERO LDS, ZERO barriers.  Swapped-operand MFMA
// (S = mfma(K,Q)); fragments loaded per-lane directly from hi/lo bf16 global
// planes; masks direct-to-register.  Block = (b, head-half, 128q x 128k).
// ---------------------------------------------------------------------------
__global__ __launch_bounds__(256)
void score_mfma5_kernel(const unsigned short* __restrict__ QHhi, const unsigned short* __restrict__ QHlo,
                        const unsigned short* __restrict__ KHhi, const unsigned short* __restrict__ KHlo,
                        const float* __restrict__ qkm, const float* __restrict__ km,
                        const float* __restrict__ pm, float4* __restrict__ partials) {
  const int z = blockIdx.z, b = z >> 1, hg = z & 1;
  const int q0 = blockIdx.y * 128, k0 = blockIdx.x * 128;
  const int tid = threadIdx.x;
  const int wid = tid >> 6, lane = tid & 63;
  const int wk = (wid >> 1) * 64, wq = (wid & 1) * 64;   // wave k/q offsets
  const int lm = lane & 15, lq = lane >> 4;

  // ---- masks -> registers, direct (no LDS bounce) ----
  f32x4 msr[4][4];   // [n(q)][m(k)] -> 4 k-consecutive values
  {
    f32x4 kmv[4];
#pragma unroll
    for (int m = 0; m < 4; m++)
      kmv[m] = *(const f32x4*)&km[b * SEQ + k0 + wk + m * 16 + lq * 4];
#pragma unroll
    for (int n = 0; n < 4; n++) {
      const size_t rowb = (size_t)(b * SEQ + q0 + wq + n * 16 + lm) * SEQ + k0 + wk;
#pragma unroll
      for (int m = 0; m < 4; m++) {
        const f32x4 qv = *(const f32x4*)&qkm[rowb + m * 16 + lq * 4];
        const f32x4 pv = *(const f32x4*)&pm[rowb + m * 16 + lq * 4];
        f32x4 o;
#pragma unroll
        for (int c = 0; c < 4; c++)
          o[c] = pv[c] > 0.f ? qv[c] + kmv[m][c] : -3.0e38f;
        msr[n][m] = o;
      }
    }
  }

  const size_t kbase = (size_t)(b * SEQ + k0 + wk + lm) * 768;
  const size_t qbase = (size_t)(b * SEQ + q0 + wq + lm) * 768;

  for (int hl = 0; hl < 6; hl++) {
    const int h = hg * 6 + hl;
    const int bh = b * NH + h;
    const int hb = h * 64;

    f32x4 acc[4][4];   // [m(k-subtile)][n(q-subtile)]
#pragma unroll
    for (int m = 0; m < 4; m++)
#pragma unroll
      for (int n = 0; n < 4; n++)
#pragma unroll
        for (int r = 0; r < 4; r++) acc[m][n][r] = 0.f;

#pragma unroll
    for (int ks = 0; ks < 2; ks++) {
      const int kc = hb + ks * 32 + lq * 8;
      s16x8 khf[4], klf[4];
#pragma unroll
      for (int m = 0; m < 4; m++) {
        const size_t off = kbase + (size_t)(m * 16) * 768 + kc;
        khf[m] = *(const s16x8*)&KHhi[off];
        klf[m] = *(const s16x8*)&KHlo[off];
      }
#pragma unroll
      for (int n = 0; n < 4; n++) {
        const size_t off = qbase + (size_t)(n * 16) * 768 + kc;
        const s16x8 qhf = *(const s16x8*)&QHhi[off];
        const s16x8 qlf = *(const s16x8*)&QHlo[off];
#pragma unroll
        for (int m = 0; m < 4; m++) {
          acc[m][n] = mfma_bf16_16x16x32(khf[m], qhf, acc[m][n]);
          acc[m][n] = mfma_bf16_16x16x32(klf[m], qhf, acc[m][n]);
          acc[m][n] = mfma_bf16_16x16x32(khf[m], qlf, acc[m][n]);
        }
      }
    }
    asm volatile("s_nop 7\n\ts_nop 7");

    // epilogue: per lane, 4 q's (n) x 16 k-candidates in registers [R9-proven]
#pragma unroll
    for (int n = 0; n < 4; n++) {
      const int qg = q0 + wq + n * 16 + lm;
      float v1 = -3.0e38f, v2 = -3.0e38f;
      int i1 = 0, i2 = 0;
#pragma unroll
      for (int m = 0; m < 4; m++)
#pragma unroll
        for (int r = 0; r < 4; r++) {
          const int kg = k0 + wk + m * 16 + lq * 4 + r;
          const float s = acc[m][n][r] * 0.125f + msr[n][m][r];
          if (better(s, kg, v1, i1)) { v2 = v1; i2 = i1; v1 = s; i1 = kg; }
          else if (better(s, kg, v2, i2)) { v2 = s; i2 = kg; }
        }
      // reduce across the 4 lq groups sharing this q (xor 16, 32)
#pragma unroll
      for (int off = 16; off < 64; off <<= 1) {
        const float w1 = __shfl_xor(v1, off); const int j1 = __shfl_xor(i1, off);
        const float w2 = __shfl_xor(v2, off); const int j2 = __shfl_xor(i2, off);
        if (better(w1, j1, v1, i1)) {
          if (better(v1, i1, w2, j2)) { v2 = v1; i2 = i1; } else { v2 = w2; i2 = j2; }
          v1 = w1; i1 = j1;
        } else if (better(w1, j1, v2, i2)) { v2 = w1; i2 = j1; }
      }
      if (lq == 0)
        partials[(size_t)(bh * SEQ + qg) * 16 + blockIdx.x * 2 + (wid >> 1)] =
            make_float4(v1, __int_as_float(i1), v2, __int_as_float(i2));
    }
  }
}

__global__ __launch_bounds__(256)
void argmax_reduce_kernel(const float4* __restrict__ partials, int* __restrict__ kmaxp,
                          float4* __restrict__ aux) {
  const int t = blockIdx.x * 256 + threadIdx.x;
  if (t >= NB * NH * SEQ) return;
  const float4* p = partials + (size_t)t * 16;
  float v1 = -3.0e38f, v2 = -3.0e38f;
  int i1 = 0, i2 = 0;
#pragma unroll
  for (int i = 0; i < 16; i++) {
    const float w1 = p[i].x; const int j1 = __float_as_int(p[i].y);
    const float w2 = p[i].z; const int j2 = __float_as_int(p[i].w);
    if (better(w1, j1, v1, i1)) {
      if (better(v1, i1, w2, j2)) { v2 = v1; i2 = i1; } else { v2 = w2; i2 = j2; }
      v1 = w1; i1 = j1;
    } else if (better(w1, j1, v2, i2)) { v2 = w1; i2 = j1; }
  }
  kmaxp[t] = i1;
  aux[t] = make_float4(v1, __int_as_float(i1), v2, __int_as_float(i2));
}

// ---------------------------------------------------------------------------
// Rescue: rows with approx top-2 gap < 2e-3 get exact fp32 rescoring from
// raw q,k,w.  Makes argmax fp32-exact.
// ---------------------------------------------------------------------------
__global__ __launch_bounds__(256)
void rescue_kernel(const float4* __restrict__ aux, const float* __restrict__ q,
                   const float* __restrict__ k, const float* __restrict__ w_qs,
                   const float* __restrict__ w_ks, const float* __restrict__ qkm,
                   const float* __restrict__ km, const float* __restrict__ pm,
                   int* __restrict__ kmaxp) {
  const int row = blockIdx.x * 4 + (threadIdx.x >> 6);
  const float4 a = aux[row];
  if (a.x - a.z > 2e-3f) return;
  const int i1 = __float_as_int(a.y), i2 = __float_as_int(a.w);
  if (i1 == i2) return;
  const int bh = row >> 10, qq = row & 1023;
  const int b = bh / NH, h = bh % NH;
  const int lane = threadIdx.x & 63;
  const float* qr = q + (size_t)(b * SEQ + qq) * Ed;
  const float* k1 = k + (size_t)(b * SEQ + i1) * Ed;
  const float* k2 = k + (size_t)(b * SEQ + i2) * Ed;
  const float* wq = w_qs + h * DKd + lane;
  const float* wk = w_ks + h * DKd + lane;
  float qd = 0.f, k1d = 0.f, k2d = 0.f;
#pragma unroll 4
  for (int e = 0; e < Ed; e++) {
    const float wqe = wq[(size_t)e * 768];
    const float wke = wk[(size_t)e * 768];
    qd  += qr[e] * wqe;
    k1d += k1[e] * wke;
    k2d += k2[e] * wke;
  }
  float s1 = qd * k1d, s2 = qd * k2d;
#pragma unroll
  for (int off = 1; off < 64; off <<= 1) {
    s1 += __shfl_xor(s1, off);
    s2 += __shfl_xor(s2, off);
  }
  const size_t m1 = (size_t)(b * SEQ + qq) * SEQ + i1;
  const size_t m2 = (size_t)(b * SEQ + qq) * SEQ + i2;
  s1 = s1 * 0.125f + (pm[m1] > 0.f ? qkm[m1] + km[b * SEQ + i1] : -3.0e38f);
  s2 = s2 * 0.125f + (pm[m2] > 0.f ? qkm[m2] + km[b * SEQ + i2] : -3.0e38f);
  if (lane == 0) kmaxp[row] = better(s1, i1, s2, i2) ? i1 : i2;
}

// ---------------------------------------------------------------------------
// v (f32) -> Vbf (bf16)
// ---------------------------------------------------------------------------
__global__ __launch_bounds__(256)
void cvt_bf16_kernel(const float* __restrict__ v, unsigned short* __restrict__ Vbf, int n4) {
  int i = blockIdx.x * 256 + threadIdx.x;
  const int stride = gridDim.x * 256;
  for (; i < n4; i += stride) {
    const f32x4 x = *(const f32x4*)&v[(size_t)i * 4];
    uint2 u;
    u.x = (unsigned)f2bf(x[0]) | ((unsigned)f2bf(x[1]) << 16);
    u.y = (unsigned)f2bf(x[2]) | ((unsigned)f2bf(x[3]) << 16);
    *(uint2*)&Vbf[(size_t)i * 4] = u;
  }
}

// ---------------------------------------------------------------------------
// MstbT[h][n][k] = (w_vs[:,h*768:+768] @ fc[h*768:+768,:])^T  (bf16)
// ---------------------------------------------------------------------------
__global__ __launch_bounds__(256)
void wvfc_gemm_kernel(const float* __restrict__ wvs, const float* __restrict__ fcw,
                      unsigned short* __restrict__ MstbT) {
  __shared__ unsigned short As[128][72];
  __shared__ unsigned short Bs[128][72];
  const int tid = threadIdx.x;
  const int h = blockIdx.z;
  const int m0 = blockIdx.x * 128, n0 = blockIdx.y * 128;
  const int wid = tid >> 6, lane = tid & 63;
  const int wr = (wid >> 1) * 64, wc = (wid & 1) * 64;
  const int lm = lane & 15, lq = lane >> 4;
  const int ar = tid >> 1, acb = (tid & 1) * 32;
  const int br = tid >> 2, bnb = (tid & 3) * 32;

  f32x4 acc[4][4];
#pragma unroll
  for (int m = 0; m < 4; m++)
#pragma unroll
    for (int n = 0; n < 4; n++)
#pragma unroll
      for (int r = 0; r < 4; r++) acc[m][n][r] = 0.f;

  for (int k0 = 0; k0 < 768; k0 += 64) {
    const float* asrc = wvs + (size_t)(m0 + ar) * HVd + h * 768 + k0 + acb;
    const float* bsrc = fcw + (size_t)(h * 768 + k0 + br) * 768 + n0 + bnb;
    f32x4 a4[8], b4[8];
#pragma unroll
    for (int i = 0; i < 8; i++) a4[i] = *(const f32x4*)&asrc[4 * i];
#pragma unroll
    for (int i = 0; i < 8; i++) b4[i] = *(const f32x4*)&bsrc[4 * i];
    __syncthreads();
#pragma unroll
    for (int i = 0; i < 4; i++) {
      s16x8 pk;
#pragma unroll
      for (int j = 0; j < 8; j++) pk[j] = (short)f2bf(a4[2 * i + (j >> 2)][j & 3]);
      *(s16x8*)&As[ar][acb + 8 * i] = pk;
    }
#pragma unroll
    for (int i = 0; i < 8; i++)
#pragma unroll
      for (int c = 0; c < 4; c++) Bs[bnb + 4 * i + c][br] = f2bf(b4[i][c]);
    __syncthreads();
#pragma unroll
    for (int ks = 0; ks < 2; ks++) {
      s16x8 af[4], bfr[4];
#pragma unroll
      for (int m = 0; m < 4; m++)
        af[m] = *(const s16x8*)&As[wr + m * 16 + lm][ks * 32 + lq * 8];
#pragma unroll
      for (int n = 0; n < 4; n++)
        bfr[n] = *(const s16x8*)&Bs[wc + n * 16 + lm][ks * 32 + lq * 8];
#pragma unroll
      for (int m = 0; m < 4; m++)
#pragma unroll
        for (int n = 0; n < 4; n++)
          acc[m][n] = mfma_bf16_16x16x32(af[m], bfr[n], acc[m][n]);
    }
  }
  asm volatile("s_nop 7\n\ts_nop 7");
#pragma unroll
  for (int m = 0; m < 4; m++)
#pragma unroll
    for (int n = 0; n < 4; n++) {
      const int grow0 = m0 + wr + m * 16 + lq * 4;
      const int gcol  = n0 + wc + n * 16 + lm;
      uint2 u;
      u.x = (unsigned)f2bf(acc[m][n][0]) | ((unsigned)f2bf(acc[m][n][1]) << 16);
      u.y = (unsigned)f2bf(acc[m][n][2]) | ((unsigned)f2bf(acc[m][n][3]) << 16);
      *(uint2*)&MstbT[(size_t)(h * 768 + gcol) * 768 + grow0] = u;
    }
}

// ---------------------------------------------------------------------------
// U[hg][4096][768p] = Vbf[4096][768] @ M_{h0+hg}  (bf16, gload_lds) [R5-proven]
// ---------------------------------------------------------------------------
__global__ __launch_bounds__(256)
void ugemm_kernel(const unsigned short* __restrict__ Vbf,
                  const unsigned short* __restrict__ MstbT,
                  unsigned short* __restrict__ U, int h0) {
  __shared__ unsigned short As[128 * 64];
  __shared__ unsigned short Bs[128 * 64];
  const int tid = threadIdx.x;
  const int h = h0 + blockIdx.z;
  const int bx = (int)blockIdx.x;
  const int sx = ((bx & 7) << 2) | (bx >> 3);
  const int m0 = sx * 128, n0 = blockIdx.y * 128;
  const int wid = tid >> 6, lane = tid & 63;
  const int wr = (wid >> 1) * 64, wc = (wid & 1) * 64;
  const int lm = lane & 15, lq = lane >> 4;
  const int srow = tid >> 3, scol = (tid & 7) * 8;
  const int ldst = (tid >> 6) * 512;

  const unsigned short* asrc = Vbf + (size_t)(m0 + srow) * 768 + scol;
  const unsigned short* bsrc = MstbT + (size_t)(h * 768 + n0 + srow) * 768 + scol;

  f32x4 acc[4][4];
#pragma unroll
  for (int m = 0; m < 4; m++)
#pragma unroll
    for (int n = 0; n < 4; n++)
#pragma unroll
      for (int r = 0; r < 4; r++) acc[m][n][r] = 0.f;

  for (int k0 = 0; k0 < 768; k0 += 64) {
#pragma unroll
    for (int j = 0; j < 4; j++)
      GLOAD16(asrc + (size_t)j * 32 * 768 + k0, &As[j * 2048 + ldst]);
#pragma unroll
    for (int j = 0; j < 4; j++)
      GLOAD16(bsrc + (size_t)j * 32 * 768 + k0, &Bs[j * 2048 + ldst]);
    __syncthreads();
#pragma unroll
    for (int ks = 0; ks < 2; ks++) {
      s16x8 af[4], bfr[4];
#pragma unroll
      for (int m = 0; m < 4; m++)
        af[m] = *(const s16x8*)&As[(wr + m * 16 + lm) * 64 + ks * 32 + lq * 8];
#pragma unroll
      for (int n = 0; n < 4; n++)
        bfr[n] = *(const s16x8*)&Bs[(wc + n * 16 + lm) * 64 + ks * 32 + lq * 8];
#pragma unroll
      for (int m = 0; m < 4; m++)
#pragma unroll
        for (int n = 0; n < 4; n++)
          acc[m][n] = mfma_bf16_16x16x32(af[m], bfr[n], acc[m][n]);
    }
    __syncthreads();
  }
  asm volatile("s_nop 7\n\ts_nop 7");
  const size_t urow0 = (size_t)blockIdx.z * 4096;
#pragma unroll
  for (int m = 0; m < 4; m++)
#pragma unroll
    for (int r = 0; r < 4; r++) {
      const int row = m0 + wr + m * 16 + lq * 4 + r;
      uint2 u;
      u.x = (unsigned)f2bf(acc[m][0][r]) | ((unsigned)f2bf(acc[m][1][r]) << 16);
      u.y = (unsigned)f2bf(acc[m][2][r]) | ((unsigned)f2bf(acc[m][3][r]) << 16);
      *(uint2*)&U[(urow0 + row) * 768 + n0 + wc + lm * 4] = u;
    }
}

// ---------------------------------------------------------------------------
// out0[row,:] (+)= sum_hg U[hg][kmax][:]  (+ v residual when h0==0)
// ---------------------------------------------------------------------------
__global__ __launch_bounds__(192)
void gathersum_kernel(const unsigned short* __restrict__ U, const int* __restrict__ kmaxp,
                      const float* __restrict__ v, float* __restrict__ out0,
                      int h0, int nhg) {
  const int row = blockIdx.x;
  const int b = row >> 10, q = row & 1023;
  const int t = threadIdx.x;
  float a0 = 0.f, a1 = 0.f, a2 = 0.f, a3 = 0.f;
  for (int hg = 0; hg < nhg; hg++) {
    const int g = kmaxp[((b * NH + h0 + hg) << 10) + q];
    const uint2 u = *(const uint2*)&U[((size_t)hg * 4096 + (b << 10) + g) * 768 + t * 4];
    a0 += bf2f_lo(u.x);
    a1 += bf2f_hi(u.x);
    a2 += bf2f_lo(u.y);
    a3 += bf2f_hi(u.y);
  }
  const int chunk = t >> 4, lmm = t & 15;
  const size_t ob = (size_t)row * 768 + chunk * 64 + lmm;
  if (h0 == 0) {
    out0[ob +  0] = a0 + v[ob +  0];
    out0[ob + 16] = a1 + v[ob + 16];
    out0[ob + 32] = a2 + v[ob + 32];
    out0[ob + 48] = a3 + v[ob + 48];
  } else {
    out0[ob +  0] += a0;
    out0[ob + 16] += a1;
    out0[ob + 32] += a2;
    out0[ob + 48] += a3;
  }
}

// ---------------------------------------------------------------------------
// attn = one-hot(kmax)
// ---------------------------------------------------------------------------
__global__ void onehot_kernel(const int* __restrict__ kmaxp, f32x4* __restrict__ attn, int n4) {
  int i = blockIdx.x * blockDim.x + threadIdx.x;
  const int stride = gridDim.x * blockDim.x;
  for (; i < n4; i += stride) {
    const int row = i >> 8;
    const int c0 = (i & 255) * 4;
    const int km = kmaxp[row];
    f32x4 o;
#pragma unroll
    for (int c = 0; c < 4; c++) o[c] = (c0 + c == km) ? 1.0f : 0.0f;
    attn[i] = o;
  }
}

// ---------------------------------------------------------------------------
extern "C" void kernel_launch(void* const* d_in, const int* in_sizes, int n_in,
                              void* d_out, int out_size, void* d_ws, size_t ws_size,
                              hipStream_t stream) {
  (void)in_sizes; (void)n_in; (void)out_size;
  const float* q       = (const float*)d_in[0];
  const float* k       = (const float*)d_in[1];
  const float* v       = (const float*)d_in[2];
  const float* qk_mask = (const float*)d_in[5];
  const float* k_mask  = (const float*)d_in[6];
  const float* pmask   = (const float*)d_in[7];
  const float* w_qs    = (const float*)d_in[8];
  const float* w_ks    = (const float*)d_in[9];
  const float* w_vs    = (const float*)d_in[10];
  const float* fc      = (const float*)d_in[11];

  float* out0 = (float*)d_out;
  float* attn = out0 + (size_t)NB * SEQ * DVd;

  // workspace layout, phase overlaps (stream-ordered):
  // p1: rawQ/K splits@0..25.2M | W splits@25.2..29.9M |
  //     QHhi@33.23M QHlo@39.52M KHhi@45.81M KHlo@52.10M (ends 58.39M)
  //     partials@0 (raw splits dead after proj), aux@12.58M (raw Khi, dead)
  // p2: MstbT@0, Vbf@14.16M, U@20.45M..{58.2M small | 95.9M big}
  // kmaxp: big -> @95.94M (after 12-head U); small -> @58.2M (KHlo tail, dead)
  char* ws = (char*)d_ws;
  unsigned short* Qhi   = (unsigned short*)ws;
  unsigned short* Qlo   = (unsigned short*)(ws + 6291456);
  unsigned short* Khi   = (unsigned short*)(ws + 12582912);
  unsigned short* Klo   = (unsigned short*)(ws + 18874368);
  unsigned short* WqThi = (unsigned short*)(ws + 25165824);
  unsigned short* WqTlo = (unsigned short*)(ws + 26345472);
  unsigned short* WkThi = (unsigned short*)(ws + 27525120);
  unsigned short* WkTlo = (unsigned short*)(ws + 28704768);
  unsigned short* QHhi  = (unsigned short*)(ws + 33226752);
  unsigned short* QHlo  = (unsigned short*)(ws + 39518208);
  unsigned short* KHhi  = (unsigned short*)(ws + 45809664);
  unsigned short* KHlo  = (unsigned short*)(ws + 52101120);
  float4* partials      = (float4*)ws;                       // 12,582,912 B
  float4* aux           = (float4*)(ws + 12582912);          //    786,432 B
  unsigned short* MstbT = (unsigned short*)ws;               // 14,155,776 B
  unsigned short* Vbf   = (unsigned short*)(ws + 14155776);  //  6,291,456 B
  unsigned short* U     = (unsigned short*)(ws + 20447232);  // up to 75.5 MB

  const bool big = ws_size >= (size_t)96141312;   // room for 12-head U + kmax
  int* kmaxp = (int*)(ws + (big ? 95944704 : 58195968));     //    196,608 B

  // 1) bf16 hi/lo splits of raw q,k and transposed splits of w_qs,w_ks
  split_qk_kernel<<<dim3(1536, 1, 2), 256, 0, stream>>>(q, k, Qhi, Qlo, Khi, Klo,
                                                        NB * SEQ * Ed / 4);
  split_wT_kernel<<<dim3(12, 12, 2), 256, 0, stream>>>(w_qs, w_ks, WqThi, WqTlo,
                                                       WkThi, WkTlo);

  // 2) projections on matrix pipe -> bf16 hi/lo planes
  qkproj_mfma_kernel<<<dim3(32, 12, 2), 256, 0, stream>>>(
      Qhi, Qlo, Khi, Klo, WqThi, WqTlo, WkThi, WkTlo, QHhi, QHlo, KHhi, KHlo);

  // 3) scores on matrix pipe, LDS-free, 6 heads/block (R10-proven)
  score_mfma5_kernel<<<dim3(8, 8, NB * 2), 256, 0, stream>>>(
      QHhi, QHlo, KHhi, KHlo, qk_mask, k_mask, pmask, partials);
  argmax_reduce_kernel<<<dim3(192), 256, 0, stream>>>(partials, kmaxp, aux);

  // 4) exact fp32 rescoring of near-ties (gap < 2e-3)
  rescue_kernel<<<dim3(12288), 256, 0, stream>>>(aux, q, k, w_qs, w_ks,
                                                 qk_mask, k_mask, pmask, kmaxp);

  // 5) v -> bf16 ; per-head M^T (bf16)
  cvt_bf16_kernel<<<dim3(3072), 256, 0, stream>>>(v, Vbf, NB * SEQ * DVd / 4);
  wvfc_gemm_kernel<<<dim3(6, 6, NH), 256, 0, stream>>>(w_vs, fc, MstbT);

  // 6) dense U_h = Vbf @ M_h, then gather+sum into out0
  if (big) {
    ugemm_kernel<<<dim3(32, 6, 12), 256, 0, stream>>>(Vbf, MstbT, U, 0);
    gathersum_kernel<<<dim3(NB * SEQ), 192, 0, stream>>>(U, kmaxp, v, out0, 0, 12);
  } else {
    ugemm_kernel<<<dim3(32, 6, 6), 256, 0, stream>>>(Vbf, MstbT, U, 0);
    gathersum_kernel<<<dim3(NB * SEQ), 192, 0, stream>>>(U, kmaxp, v, out0, 0, 6);
    ugemm_kernel<<<dim3(32, 6, 6), 256, 0, stream>>>(Vbf, MstbT, U, 6);
    gathersum_kernel<<<dim3(NB * SEQ), 192, 0, stream>>>(U, kmaxp, v, out0, 6, 6);
  }

  // 7) attn = one-hot(kmax)
  onehot_kernel<<<dim3(2048), 256, 0, stream>>>(kmaxp, (f32x4*)attn,
                                                (int)((size_t)NB * NH * SEQ * SEQ / 4));
}

// Round 14
// 413.656 us; speedup vs baseline: 1.0601x; 1.0069x over previous
//
#include <hip/hip_runtime.h>

// Problem constants
constexpr int NB  = 4;
constexpr int NH  = 12;
constexpr int SEQ = 1024;   // LQ == LK
constexpr int DKd = 64;
constexpr int DVd = 768;
constexpr int Ed  = 768;    // E == H*DK
constexpr int HVd = 9216;   // H*DV

typedef float f32x4 __attribute__((ext_vector_type(4)));
typedef short s16x8 __attribute__((ext_vector_type(8)));

__device__ __forceinline__ unsigned short f2bf(float f) {
  unsigned int u = __builtin_bit_cast(unsigned int, f);
  u += 0x7fffu + ((u >> 16) & 1u);          // RNE
  return (unsigned short)(u >> 16);
}
__device__ __forceinline__ float bf2f(unsigned short h) {
  return __builtin_bit_cast(float, (unsigned int)h << 16);
}
__device__ __forceinline__ float bf2f_lo(unsigned int u) {
  return __builtin_bit_cast(float, u << 16);
}
__device__ __forceinline__ float bf2f_hi(unsigned int u) {
  return __builtin_bit_cast(float, u & 0xffff0000u);
}
// argmax comparator: higher value wins; ties -> lower index (matches jnp.argmax)
__device__ __forceinline__ bool better(float va, int ia, float vb, int ib) {
  return va > vb || (va == vb && ia < ib);
}

__device__ __forceinline__ f32x4 mfma_bf16_16x16x32(s16x8 a, s16x8 b, f32x4 c) {
  asm("v_mfma_f32_16x16x32_bf16 %0, %1, %2, %0" : "+v"(c) : "v"(a), "v"(b));
  return c;
}

#define GLOAD16(g, l)                                                          \
  __builtin_amdgcn_global_load_lds(                                            \
      (const __attribute__((address_space(1))) unsigned int*)(g),              \
      (__attribute__((address_space(3))) unsigned int*)(l), 16, 0, 0)

// ---------------------------------------------------------------------------
// q,k (f32) -> hi/lo bf16 split (Markidis)   [R5-proven]
// ---------------------------------------------------------------------------
__global__ __launch_bounds__(256)
void split_qk_kernel(const float* __restrict__ q, const float* __restrict__ k,
                     unsigned short* __restrict__ Qhi, unsigned short* __restrict__ Qlo,
                     unsigned short* __restrict__ Khi, unsigned short* __restrict__ Klo,
                     int n4) {
  const float* src = blockIdx.z ? k : q;
  unsigned short* hi = blockIdx.z ? Khi : Qhi;
  unsigned short* lo = blockIdx.z ? Klo : Qlo;
  int i = blockIdx.x * 256 + threadIdx.x;
  const int stride = gridDim.x * 256;
  for (; i < n4; i += stride) {
    const f32x4 x = *(const f32x4*)&src[(size_t)i * 4];
    unsigned short h[4], l[4];
#pragma unroll
    for (int c = 0; c < 4; c++) {
      h[c] = f2bf(x[c]);
      l[c] = f2bf(x[c] - bf2f(h[c]));
    }
    uint2 uh, ul;
    uh.x = (unsigned)h[0] | ((unsigned)h[1] << 16);
    uh.y = (unsigned)h[2] | ((unsigned)h[3] << 16);
    ul.x = (unsigned)l[0] | ((unsigned)l[1] << 16);
    ul.y = (unsigned)l[2] | ((unsigned)l[3] << 16);
    *(uint2*)&hi[(size_t)i * 4] = uh;
    *(uint2*)&lo[(size_t)i * 4] = ul;
  }
}

// ---------------------------------------------------------------------------
// w (f32 [e][n]) -> WT hi/lo bf16 [n][e]  (transpose + split)   [R5-proven]
// ---------------------------------------------------------------------------
__global__ __launch_bounds__(256)
void split_wT_kernel(const float* __restrict__ w_qs, const float* __restrict__ w_ks,
                     unsigned short* __restrict__ WqThi, unsigned short* __restrict__ WqTlo,
                     unsigned short* __restrict__ WkThi, unsigned short* __restrict__ WkTlo) {
  __shared__ float Ts[64][68];
  const float* src = blockIdx.z ? w_ks : w_qs;
  unsigned short* hi = blockIdx.z ? WkThi : WqThi;
  unsigned short* lo = blockIdx.z ? WkTlo : WqTlo;
  const int e0 = blockIdx.x * 64, n0 = blockIdx.y * 64;
  const int tid = threadIdx.x;
  const int row = tid >> 2, cc = (tid & 3) * 16;
#pragma unroll
  for (int j = 0; j < 4; j++)
    *(f32x4*)&Ts[row][cc + 4 * j] = *(const f32x4*)&src[(size_t)(e0 + row) * 768 + n0 + cc + 4 * j];
  __syncthreads();
  const int r = tid >> 2, cs = (tid & 3) * 16;
  s16x8 ph[2], pl[2];
#pragma unroll
  for (int j = 0; j < 16; j++) {
    const float v = Ts[cs + j][r];
    const unsigned short h = f2bf(v);
    const unsigned short l = f2bf(v - bf2f(h));
    ph[j >> 3][j & 7] = (short)h;
    pl[j >> 3][j & 7] = (short)l;
  }
  const size_t ob = (size_t)(n0 + r) * 768 + e0 + cs;
  *(s16x8*)&hi[ob] = ph[0];
  *(s16x8*)&hi[ob + 8] = ph[1];
  *(s16x8*)&lo[ob] = pl[0];
  *(s16x8*)&lo[ob + 8] = pl[1];
}

// ---------------------------------------------------------------------------
// Projected heads = A @ W via 3-term bf16 MFMA; OUTPUT = bf16 hi/lo planes
// (same split arithmetic as split_qk).  Body = R5-proven text.
// ---------------------------------------------------------------------------
__global__ __launch_bounds__(256)
void qkproj_mfma_kernel(const unsigned short* __restrict__ Qhi, const unsigned short* __restrict__ Qlo,
                        const unsigned short* __restrict__ Khi, const unsigned short* __restrict__ Klo,
                        const unsigned short* __restrict__ WqThi, const unsigned short* __restrict__ WqTlo,
                        const unsigned short* __restrict__ WkThi, const unsigned short* __restrict__ WkTlo,
                        unsigned short* __restrict__ QHhi, unsigned short* __restrict__ QHlo,
                        unsigned short* __restrict__ KHhi, unsigned short* __restrict__ KHlo) {
  const unsigned short* Ahi = blockIdx.z ? Khi : Qhi;
  const unsigned short* Alo = blockIdx.z ? Klo : Qlo;
  const unsigned short* Bhi = blockIdx.z ? WkThi : WqThi;
  const unsigned short* Blo = blockIdx.z ? WkTlo : WqTlo;
  unsigned short* Chi = blockIdx.z ? KHhi : QHhi;
  unsigned short* Clo = blockIdx.z ? KHlo : QHlo;
  __shared__ unsigned short AhiS[128 * 64], AloS[128 * 64];
  __shared__ unsigned short BhiS[64 * 64], BloS[64 * 64];
  const int tid = threadIdx.x;
  const int wid = tid >> 6, lane = tid & 63;
  const int m0 = blockIdx.x * 128, n0 = blockIdx.y * 64;
  const int wr = (wid >> 1) * 64, wc = (wid & 1) * 32;
  const int lm = lane & 15, lq = lane >> 4;
  const int srow = wid * 8 + (lane >> 3);
  const int scols = (((lane & 7) * 16) ^ ((srow & 7) << 4)) >> 1;
  const int ldst = wid * 512;
  const int xs = (lm & 7) << 3;

  const unsigned short* ahi0 = Ahi + (size_t)(m0 + srow) * 768 + scols;
  const unsigned short* alo0 = Alo + (size_t)(m0 + srow) * 768 + scols;
  const unsigned short* bhi0 = Bhi + (size_t)(n0 + srow) * 768 + scols;
  const unsigned short* blo0 = Blo + (size_t)(n0 + srow) * 768 + scols;

  f32x4 acc[4][2];
#pragma unroll
  for (int m = 0; m < 4; m++)
#pragma unroll
    for (int n = 0; n < 2; n++)
#pragma unroll
      for (int r = 0; r < 4; r++) acc[m][n][r] = 0.f;

  for (int k0 = 0; k0 < 768; k0 += 64) {
#pragma unroll
    for (int j = 0; j < 4; j++) {
      GLOAD16(ahi0 + (size_t)j * 32 * 768 + k0, &AhiS[j * 2048 + ldst]);
      GLOAD16(alo0 + (size_t)j * 32 * 768 + k0, &AloS[j * 2048 + ldst]);
    }
#pragma unroll
    for (int j = 0; j < 2; j++) {
      GLOAD16(bhi0 + (size_t)j * 32 * 768 + k0, &BhiS[j * 2048 + ldst]);
      GLOAD16(blo0 + (size_t)j * 32 * 768 + k0, &BloS[j * 2048 + ldst]);
    }
    __syncthreads();
#pragma unroll
    for (int ks = 0; ks < 2; ks++) {
      const int kc = (ks * 32 + lq * 8) ^ xs;
      s16x8 ah[4], al[4], bh[2], bl[2];
#pragma unroll
      for (int m = 0; m < 4; m++) {
        ah[m] = *(const s16x8*)&AhiS[(wr + m * 16 + lm) * 64 + kc];
        al[m] = *(const s16x8*)&AloS[(wr + m * 16 + lm) * 64 + kc];
      }
#pragma unroll
      for (int n = 0; n < 2; n++) {
        bh[n] = *(const s16x8*)&BhiS[(wc + n * 16 + lm) * 64 + kc];
        bl[n] = *(const s16x8*)&BloS[(wc + n * 16 + lm) * 64 + kc];
      }
#pragma unroll
      for (int m = 0; m < 4; m++)
#pragma unroll
        for (int n = 0; n < 2; n++) {
          acc[m][n] = mfma_bf16_16x16x32(ah[m], bh[n], acc[m][n]);
          acc[m][n] = mfma_bf16_16x16x32(al[m], bh[n], acc[m][n]);
          acc[m][n] = mfma_bf16_16x16x32(ah[m], bl[n], acc[m][n]);
        }
    }
    __syncthreads();
  }
  asm volatile("s_nop 7\n\ts_nop 7");
#pragma unroll
  for (int m = 0; m < 4; m++)
#pragma unroll
    for (int n = 0; n < 2; n++)
#pragma unroll
      for (int r = 0; r < 4; r++) {
        const float vv = acc[m][n][r];
        const unsigned short hh = f2bf(vv);
        const unsigned short ll = f2bf(vv - bf2f(hh));
        const size_t off =
            (size_t)(m0 + wr + m * 16 + lq * 4 + r) * 768 + n0 + wc + n * 16 + lm;
        Chi[off] = hh;
        Clo[off] = ll;
      }
}

// ---------------------------------------------------------------------------
// Score v5 [R10-proven]: ZERO LDS, ZERO barriers.  Swapped-operand MFMA
// (S = mfma(K,Q)); fragments loaded per-lane directly from hi/lo bf16 global
// planes; masks direct-to-register.  Block = (b, head-half, 128q x 128k).
// ---------------------------------------------------------------------------
__global__ __launch_bounds__(256)
void score_mfma5_kernel(const unsigned short* __restrict__ QHhi, const unsigned short* __restrict__ QHlo,
                        const unsigned short* __restrict__ KHhi, const unsigned short* __restrict__ KHlo,
                        const float* __restrict__ qkm, const float* __restrict__ km,
                        const float* __restrict__ pm, float4* __restrict__ partials) {
  const int z = blockIdx.z, b = z >> 1, hg = z & 1;
  const int q0 = blockIdx.y * 128, k0 = blockIdx.x * 128;
  const int tid = threadIdx.x;
  const int wid = tid >> 6, lane = tid & 63;
  const int wk = (wid >> 1) * 64, wq = (wid & 1) * 64;   // wave k/q offsets
  const int lm = lane & 15, lq = lane >> 4;

  // ---- masks -> registers, direct (no LDS bounce) ----
  f32x4 msr[4][4];   // [n(q)][m(k)] -> 4 k-consecutive values
  {
    f32x4 kmv[4];
#pragma unroll
    for (int m = 0; m < 4; m++)
      kmv[m] = *(const f32x4*)&km[b * SEQ + k0 + wk + m * 16 + lq * 4];
#pragma unroll
    for (int n = 0; n < 4; n++) {
      const size_t rowb = (size_t)(b * SEQ + q0 + wq + n * 16 + lm) * SEQ + k0 + wk;
#pragma unroll
      for (int m = 0; m < 4; m++) {
        const f32x4 qv = *(const f32x4*)&qkm[rowb + m * 16 + lq * 4];
        const f32x4 pv = *(const f32x4*)&pm[rowb + m * 16 + lq * 4];
        f32x4 o;
#pragma unroll
        for (int c = 0; c < 4; c++)
          o[c] = pv[c] > 0.f ? qv[c] + kmv[m][c] : -3.0e38f;
        msr[n][m] = o;
      }
    }
  }

  const size_t kbase = (size_t)(b * SEQ + k0 + wk + lm) * 768;
  const size_t qbase = (size_t)(b * SEQ + q0 + wq + lm) * 768;

  for (int hl = 0; hl < 6; hl++) {
    const int h = hg * 6 + hl;
    const int bh = b * NH + h;
    const int hb = h * 64;

    f32x4 acc[4][4];   // [m(k-subtile)][n(q-subtile)]
#pragma unroll
    for (int m = 0; m < 4; m++)
#pragma unroll
      for (int n = 0; n < 4; n++)
#pragma unroll
        for (int r = 0; r < 4; r++) acc[m][n][r] = 0.f;

#pragma unroll
    for (int ks = 0; ks < 2; ks++) {
      const int kc = hb + ks * 32 + lq * 8;
      s16x8 khf[4], klf[4];
#pragma unroll
      for (int m = 0; m < 4; m++) {
        const size_t off = kbase + (size_t)(m * 16) * 768 + kc;
        khf[m] = *(const s16x8*)&KHhi[off];
        klf[m] = *(const s16x8*)&KHlo[off];
      }
#pragma unroll
      for (int n = 0; n < 4; n++) {
        const size_t off = qbase + (size_t)(n * 16) * 768 + kc;
        const s16x8 qhf = *(const s16x8*)&QHhi[off];
        const s16x8 qlf = *(const s16x8*)&QHlo[off];
#pragma unroll
        for (int m = 0; m < 4; m++) {
          acc[m][n] = mfma_bf16_16x16x32(khf[m], qhf, acc[m][n]);
          acc[m][n] = mfma_bf16_16x16x32(klf[m], qhf, acc[m][n]);
          acc[m][n] = mfma_bf16_16x16x32(khf[m], qlf, acc[m][n]);
        }
      }
    }
    asm volatile("s_nop 7\n\ts_nop 7");

    // epilogue: per lane, 4 q's (n) x 16 k-candidates in registers [R9-proven]
#pragma unroll
    for (int n = 0; n < 4; n++) {
      const int qg = q0 + wq + n * 16 + lm;
      float v1 = -3.0e38f, v2 = -3.0e38f;
      int i1 = 0, i2 = 0;
#pragma unroll
      for (int m = 0; m < 4; m++)
#pragma unroll
        for (int r = 0; r < 4; r++) {
          const int kg = k0 + wk + m * 16 + lq * 4 + r;
          const float s = acc[m][n][r] * 0.125f + msr[n][m][r];
          if (better(s, kg, v1, i1)) { v2 = v1; i2 = i1; v1 = s; i1 = kg; }
          else if (better(s, kg, v2, i2)) { v2 = s; i2 = kg; }
        }
      // reduce across the 4 lq groups sharing this q (xor 16, 32)
#pragma unroll
      for (int off = 16; off < 64; off <<= 1) {
        const float w1 = __shfl_xor(v1, off); const int j1 = __shfl_xor(i1, off);
        const float w2 = __shfl_xor(v2, off); const int j2 = __shfl_xor(i2, off);
        if (better(w1, j1, v1, i1)) {
          if (better(v1, i1, w2, j2)) { v2 = v1; i2 = i1; } else { v2 = w2; i2 = j2; }
          v1 = w1; i1 = j1;
        } else if (better(w1, j1, v2, i2)) { v2 = w1; i2 = j1; }
      }
      if (lq == 0)
        partials[(size_t)(bh * SEQ + qg) * 16 + blockIdx.x * 2 + (wid >> 1)] =
            make_float4(v1, __int_as_float(i1), v2, __int_as_float(i2));
    }
  }
}

__global__ __launch_bounds__(256)
void argmax_reduce_kernel(const float4* __restrict__ partials, int* __restrict__ kmaxp,
                          float4* __restrict__ aux) {
  const int t = blockIdx.x * 256 + threadIdx.x;
  if (t >= NB * NH * SEQ) return;
  const float4* p = partials + (size_t)t * 16;
  float v1 = -3.0e38f, v2 = -3.0e38f;
  int i1 = 0, i2 = 0;
#pragma unroll
  for (int i = 0; i < 16; i++) {
    const float w1 = p[i].x; const int j1 = __float_as_int(p[i].y);
    const float w2 = p[i].z; const int j2 = __float_as_int(p[i].w);
    if (better(w1, j1, v1, i1)) {
      if (better(v1, i1, w2, j2)) { v2 = v1; i2 = i1; } else { v2 = w2; i2 = j2; }
      v1 = w1; i1 = j1;
    } else if (better(w1, j1, v2, i2)) { v2 = w1; i2 = j1; }
  }
  kmaxp[t] = i1;
  aux[t] = make_float4(v1, __int_as_float(i1), v2, __int_as_float(i2));
}

// ---------------------------------------------------------------------------
// Rescue: rows with approx top-2 gap < 2e-3 get exact fp32 rescoring from
// raw q,k,w.  Makes argmax fp32-exact.
// ---------------------------------------------------------------------------
__global__ __launch_bounds__(256)
void rescue_kernel(const float4* __restrict__ aux, const float* __restrict__ q,
                   const float* __restrict__ k, const float* __restrict__ w_qs,
                   const float* __restrict__ w_ks, const float* __restrict__ qkm,
                   const float* __restrict__ km, const float* __restrict__ pm,
                   int* __restrict__ kmaxp) {
  const int row = blockIdx.x * 4 + (threadIdx.x >> 6);
  const float4 a = aux[row];
  if (a.x - a.z > 2e-3f) return;
  const int i1 = __float_as_int(a.y), i2 = __float_as_int(a.w);
  if (i1 == i2) return;
  const int bh = row >> 10, qq = row & 1023;
  const int b = bh / NH, h = bh % NH;
  const int lane = threadIdx.x & 63;
  const float* qr = q + (size_t)(b * SEQ + qq) * Ed;
  const float* k1 = k + (size_t)(b * SEQ + i1) * Ed;
  const float* k2 = k + (size_t)(b * SEQ + i2) * Ed;
  const float* wq = w_qs + h * DKd + lane;
  const float* wk = w_ks + h * DKd + lane;
  float qd = 0.f, k1d = 0.f, k2d = 0.f;
#pragma unroll 4
  for (int e = 0; e < Ed; e++) {
    const float wqe = wq[(size_t)e * 768];
    const float wke = wk[(size_t)e * 768];
    qd  += qr[e] * wqe;
    k1d += k1[e] * wke;
    k2d += k2[e] * wke;
  }
  float s1 = qd * k1d, s2 = qd * k2d;
#pragma unroll
  for (int off = 1; off < 64; off <<= 1) {
    s1 += __shfl_xor(s1, off);
    s2 += __shfl_xor(s2, off);
  }
  const size_t m1 = (size_t)(b * SEQ + qq) * SEQ + i1;
  const size_t m2 = (size_t)(b * SEQ + qq) * SEQ + i2;
  s1 = s1 * 0.125f + (pm[m1] > 0.f ? qkm[m1] + km[b * SEQ + i1] : -3.0e38f);
  s2 = s2 * 0.125f + (pm[m2] > 0.f ? qkm[m2] + km[b * SEQ + i2] : -3.0e38f);
  if (lane == 0) kmaxp[row] = better(s1, i1, s2, i2) ? i1 : i2;
}

// ---------------------------------------------------------------------------
// v (f32) -> Vbf (bf16)
// ---------------------------------------------------------------------------
__global__ __launch_bounds__(256)
void cvt_bf16_kernel(const float* __restrict__ v, unsigned short* __restrict__ Vbf, int n4) {
  int i = blockIdx.x * 256 + threadIdx.x;
  const int stride = gridDim.x * 256;
  for (; i < n4; i += stride) {
    const f32x4 x = *(const f32x4*)&v[(size_t)i * 4];
    uint2 u;
    u.x = (unsigned)f2bf(x[0]) | ((unsigned)f2bf(x[1]) << 16);
    u.y = (unsigned)f2bf(x[2]) | ((unsigned)f2bf(x[3]) << 16);
    *(uint2*)&Vbf[(size_t)i * 4] = u;
  }
}

// ---------------------------------------------------------------------------
// MstbT[h][n][k] = (w_vs[:,h*768:+768] @ fc[h*768:+768,:])^T  (bf16)
// ---------------------------------------------------------------------------
__global__ __launch_bounds__(256)
void wvfc_gemm_kernel(const float* __restrict__ wvs, const float* __restrict__ fcw,
                      unsigned short* __restrict__ MstbT) {
  __shared__ unsigned short As[128][72];
  __shared__ unsigned short Bs[128][72];
  const int tid = threadIdx.x;
  const int h = blockIdx.z;
  const int m0 = blockIdx.x * 128, n0 = blockIdx.y * 128;
  const int wid = tid >> 6, lane = tid & 63;
  const int wr = (wid >> 1) * 64, wc = (wid & 1) * 64;
  const int lm = lane & 15, lq = lane >> 4;
  const int ar = tid >> 1, acb = (tid & 1) * 32;
  const int br = tid >> 2, bnb = (tid & 3) * 32;

  f32x4 acc[4][4];
#pragma unroll
  for (int m = 0; m < 4; m++)
#pragma unroll
    for (int n = 0; n < 4; n++)
#pragma unroll
      for (int r = 0; r < 4; r++) acc[m][n][r] = 0.f;

  for (int k0 = 0; k0 < 768; k0 += 64) {
    const float* asrc = wvs + (size_t)(m0 + ar) * HVd + h * 768 + k0 + acb;
    const float* bsrc = fcw + (size_t)(h * 768 + k0 + br) * 768 + n0 + bnb;
    f32x4 a4[8], b4[8];
#pragma unroll
    for (int i = 0; i < 8; i++) a4[i] = *(const f32x4*)&asrc[4 * i];
#pragma unroll
    for (int i = 0; i < 8; i++) b4[i] = *(const f32x4*)&bsrc[4 * i];
    __syncthreads();
#pragma unroll
    for (int i = 0; i < 4; i++) {
      s16x8 pk;
#pragma unroll
      for (int j = 0; j < 8; j++) pk[j] = (short)f2bf(a4[2 * i + (j >> 2)][j & 3]);
      *(s16x8*)&As[ar][acb + 8 * i] = pk;
    }
#pragma unroll
    for (int i = 0; i < 8; i++)
#pragma unroll
      for (int c = 0; c < 4; c++) Bs[bnb + 4 * i + c][br] = f2bf(b4[i][c]);
    __syncthreads();
#pragma unroll
    for (int ks = 0; ks < 2; ks++) {
      s16x8 af[4], bfr[4];
#pragma unroll
      for (int m = 0; m < 4; m++)
        af[m] = *(const s16x8*)&As[wr + m * 16 + lm][ks * 32 + lq * 8];
#pragma unroll
      for (int n = 0; n < 4; n++)
        bfr[n] = *(const s16x8*)&Bs[wc + n * 16 + lm][ks * 32 + lq * 8];
#pragma unroll
      for (int m = 0; m < 4; m++)
#pragma unroll
        for (int n = 0; n < 4; n++)
          acc[m][n] = mfma_bf16_16x16x32(af[m], bfr[n], acc[m][n]);
    }
  }
  asm volatile("s_nop 7\n\ts_nop 7");
#pragma unroll
  for (int m = 0; m < 4; m++)
#pragma unroll
    for (int n = 0; n < 4; n++) {
      const int grow0 = m0 + wr + m * 16 + lq * 4;
      const int gcol  = n0 + wc + n * 16 + lm;
      uint2 u;
      u.x = (unsigned)f2bf(acc[m][n][0]) | ((unsigned)f2bf(acc[m][n][1]) << 16);
      u.y = (unsigned)f2bf(acc[m][n][2]) | ((unsigned)f2bf(acc[m][n][3]) << 16);
      *(uint2*)&MstbT[(size_t)(h * 768 + gcol) * 768 + grow0] = u;
    }
}

// ---------------------------------------------------------------------------
// U[hg][4096][768p] = Vbf[4096][768] @ M_{h0+hg}  (bf16, gload_lds) [R5-proven]
// ---------------------------------------------------------------------------
__global__ __launch_bounds__(256)
void ugemm_kernel(const unsigned short* __restrict__ Vbf,
                  const unsigned short* __restrict__ MstbT,
                  unsigned short* __restrict__ U, int h0) {
  __shared__ unsigned short As[128 * 64];
  __shared__ unsigned short Bs[128 * 64];
  const int tid = threadIdx.x;
  const int h = h0 + blockIdx.z;
  const int bx = (int)blockIdx.x;
  const int sx = ((bx & 7) << 2) | (bx >> 3);
  const int m0 = sx * 128, n0 = blockIdx.y * 128;
  const int wid = tid >> 6, lane = tid & 63;
  const int wr = (wid >> 1) * 64, wc = (wid & 1) * 64;
  const int lm = lane & 15, lq = lane >> 4;
  const int srow = tid >> 3, scol = (tid & 7) * 8;
  const int ldst = (tid >> 6) * 512;

  const unsigned short* asrc = Vbf + (size_t)(m0 + srow) * 768 + scol;
  const unsigned short* bsrc = MstbT + (size_t)(h * 768 + n0 + srow) * 768 + scol;

  f32x4 acc[4][4];
#pragma unroll
  for (int m = 0; m < 4; m++)
#pragma unroll
    for (int n = 0; n < 4; n++)
#pragma unroll
      for (int r = 0; r < 4; r++) acc[m][n][r] = 0.f;

  for (int k0 = 0; k0 < 768; k0 += 64) {
#pragma unroll
    for (int j = 0; j < 4; j++)
      GLOAD16(asrc + (size_t)j * 32 * 768 + k0, &As[j * 2048 + ldst]);
#pragma unroll
    for (int j = 0; j < 4; j++)
      GLOAD16(bsrc + (size_t)j * 32 * 768 + k0, &Bs[j * 2048 + ldst]);
    __syncthreads();
#pragma unroll
    for (int ks = 0; ks < 2; ks++) {
      s16x8 af[4], bfr[4];
#pragma unroll
      for (int m = 0; m < 4; m++)
        af[m] = *(const s16x8*)&As[(wr + m * 16 + lm) * 64 + ks * 32 + lq * 8];
#pragma unroll
      for (int n = 0; n < 4; n++)
        bfr[n] = *(const s16x8*)&Bs[(wc + n * 16 + lm) * 64 + ks * 32 + lq * 8];
#pragma unroll
      for (int m = 0; m < 4; m++)
#pragma unroll
        for (int n = 0; n < 4; n++)
          acc[m][n] = mfma_bf16_16x16x32(af[m], bfr[n], acc[m][n]);
    }
    __syncthreads();
  }
  asm volatile("s_nop 7\n\ts_nop 7");
  const size_t urow0 = (size_t)blockIdx.z * 4096;
#pragma unroll
  for (int m = 0; m < 4; m++)
#pragma unroll
    for (int r = 0; r < 4; r++) {
      const int row = m0 + wr + m * 16 + lq * 4 + r;
      uint2 u;
      u.x = (unsigned)f2bf(acc[m][0][r]) | ((unsigned)f2bf(acc[m][1][r]) << 16);
      u.y = (unsigned)f2bf(acc[m][2][r]) | ((unsigned)f2bf(acc[m][3][r]) << 16);
      *(uint2*)&U[(urow0 + row) * 768 + n0 + wc + lm * 4] = u;
    }
}

// ---------------------------------------------------------------------------
// out0[row,:] (+)= sum_hg U[hg][kmax][:]  (+ v residual when h0==0)
// ---------------------------------------------------------------------------
__global__ __launch_bounds__(192)
void gathersum_kernel(const unsigned short* __restrict__ U, const int* __restrict__ kmaxp,
                      const float* __restrict__ v, float* __restrict__ out0,
                      int h0, int nhg) {
  const int row = blockIdx.x;
  const int b = row >> 10, q = row & 1023;
  const int t = threadIdx.x;
  float a0 = 0.f, a1 = 0.f, a2 = 0.f, a3 = 0.f;
  for (int hg = 0; hg < nhg; hg++) {
    const int g = kmaxp[((b * NH + h0 + hg) << 10) + q];
    const uint2 u = *(const uint2*)&U[((size_t)hg * 4096 + (b << 10) + g) * 768 + t * 4];
    a0 += bf2f_lo(u.x);
    a1 += bf2f_hi(u.x);
    a2 += bf2f_lo(u.y);
    a3 += bf2f_hi(u.y);
  }
  const int chunk = t >> 4, lmm = t & 15;
  const size_t ob = (size_t)row * 768 + chunk * 64 + lmm;
  if (h0 == 0) {
    out0[ob +  0] = a0 + v[ob +  0];
    out0[ob + 16] = a1 + v[ob + 16];
    out0[ob + 32] = a2 + v[ob + 32];
    out0[ob + 48] = a3 + v[ob + 48];
  } else {
    out0[ob +  0] += a0;
    out0[ob + 16] += a1;
    out0[ob + 32] += a2;
    out0[ob + 48] += a3;
  }
}

// ---------------------------------------------------------------------------
// attn = one-hot(kmax)
// ---------------------------------------------------------------------------
__global__ void onehot_kernel(const int* __restrict__ kmaxp, f32x4* __restrict__ attn, int n4) {
  int i = blockIdx.x * blockDim.x + threadIdx.x;
  const int stride = gridDim.x * blockDim.x;
  for (; i < n4; i += stride) {
    const int row = i >> 8;
    const int c0 = (i & 255) * 4;
    const int km = kmaxp[row];
    f32x4 o;
#pragma unroll
    for (int c = 0; c < 4; c++) o[c] = (c0 + c == km) ? 1.0f : 0.0f;
    attn[i] = o;
  }
}

// ---------------------------------------------------------------------------
extern "C" void kernel_launch(void* const* d_in, const int* in_sizes, int n_in,
                              void* d_out, int out_size, void* d_ws, size_t ws_size,
                              hipStream_t stream) {
  (void)in_sizes; (void)n_in; (void)out_size;
  const float* q       = (const float*)d_in[0];
  const float* k       = (const float*)d_in[1];
  const float* v       = (const float*)d_in[2];
  const float* qk_mask = (const float*)d_in[5];
  const float* k_mask  = (const float*)d_in[6];
  const float* pmask   = (const float*)d_in[7];
  const float* w_qs    = (const float*)d_in[8];
  const float* w_ks    = (const float*)d_in[9];
  const float* w_vs    = (const float*)d_in[10];
  const float* fc      = (const float*)d_in[11];

  float* out0 = (float*)d_out;
  float* attn = out0 + (size_t)NB * SEQ * DVd;

  // workspace layout, phase overlaps (stream-ordered):
  // p1: rawQ/K splits@0..25.2M | W splits@25.2..29.9M |
  //     QHhi@33.23M QHlo@39.52M KHhi@45.81M KHlo@52.10M (ends 58.39M)
  //     partials@0 (raw splits dead after proj), aux@12.58M (raw Khi, dead)
  // p2: MstbT@0, Vbf@14.16M, U@20.45M..{58.2M small | 95.9M big}
  // kmaxp: big -> @95.94M (after 12-head U); small -> @58.2M (KHlo tail, dead)
  char* ws = (char*)d_ws;
  unsigned short* Qhi   = (unsigned short*)ws;
  unsigned short* Qlo   = (unsigned short*)(ws + 6291456);
  unsigned short* Khi   = (unsigned short*)(ws + 12582912);
  unsigned short* Klo   = (unsigned short*)(ws + 18874368);
  unsigned short* WqThi = (unsigned short*)(ws + 25165824);
  unsigned short* WqTlo = (unsigned short*)(ws + 26345472);
  unsigned short* WkThi = (unsigned short*)(ws + 27525120);
  unsigned short* WkTlo = (unsigned short*)(ws + 28704768);
  unsigned short* QHhi  = (unsigned short*)(ws + 33226752);
  unsigned short* QHlo  = (unsigned short*)(ws + 39518208);
  unsigned short* KHhi  = (unsigned short*)(ws + 45809664);
  unsigned short* KHlo  = (unsigned short*)(ws + 52101120);
  float4* partials      = (float4*)ws;                       // 12,582,912 B
  float4* aux           = (float4*)(ws + 12582912);          //    786,432 B
  unsigned short* MstbT = (unsigned short*)ws;               // 14,155,776 B
  unsigned short* Vbf   = (unsigned short*)(ws + 14155776);  //  6,291,456 B
  unsigned short* U     = (unsigned short*)(ws + 20447232);  // up to 75.5 MB

  const bool big = ws_size >= (size_t)96141312;   // room for 12-head U + kmax
  int* kmaxp = (int*)(ws + (big ? 95944704 : 58195968));     //    196,608 B

  // 1) bf16 hi/lo splits of raw q,k and transposed splits of w_qs,w_ks
  split_qk_kernel<<<dim3(1536, 1, 2), 256, 0, stream>>>(q, k, Qhi, Qlo, Khi, Klo,
                                                        NB * SEQ * Ed / 4);
  split_wT_kernel<<<dim3(12, 12, 2), 256, 0, stream>>>(w_qs, w_ks, WqThi, WqTlo,
                                                       WkThi, WkTlo);

  // 2) projections on matrix pipe -> bf16 hi/lo planes
  qkproj_mfma_kernel<<<dim3(32, 12, 2), 256, 0, stream>>>(
      Qhi, Qlo, Khi, Klo, WqThi, WqTlo, WkThi, WkTlo, QHhi, QHlo, KHhi, KHlo);

  // 3) scores on matrix pipe, LDS-free, 6 heads/block (R10-proven)
  score_mfma5_kernel<<<dim3(8, 8, NB * 2), 256, 0, stream>>>(
      QHhi, QHlo, KHhi, KHlo, qk_mask, k_mask, pmask, partials);
  argmax_reduce_kernel<<<dim3(192), 256, 0, stream>>>(partials, kmaxp, aux);

  // 4) exact fp32 rescoring of near-ties (gap < 2e-3)
  rescue_kernel<<<dim3(12288), 256, 0, stream>>>(aux, q, k, w_qs, w_ks,
                                                 qk_mask, k_mask, pmask, kmaxp);

  // 5) v -> bf16 ; per-head M^T (bf16)
  cvt_bf16_kernel<<<dim3(3072), 256, 0, stream>>>(v, Vbf, NB * SEQ * DVd / 4);
  wvfc_gemm_kernel<<<dim3(6, 6, NH), 256, 0, stream>>>(w_vs, fc, MstbT);

  // 6) dense U_h = Vbf @ M_h, then gather+sum into out0
  if (big) {
    ugemm_kernel<<<dim3(32, 6, 12), 256, 0, stream>>>(Vbf, MstbT, U, 0);
    gathersum_kernel<<<dim3(NB * SEQ), 192, 0, stream>>>(U, kmaxp, v, out0, 0, 12);
  } else {
    ugemm_kernel<<<dim3(32, 6, 6), 256, 0, stream>>>(Vbf, MstbT, U, 0);
    gathersum_kernel<<<dim3(NB * SEQ), 192, 0, stream>>>(U, kmaxp, v, out0, 0, 6);
    ugemm_kernel<<<dim3(32, 6, 6), 256, 0, stream>>>(Vbf, MstbT, U, 6);
    gathersum_kernel<<<dim3(NB * SEQ), 192, 0, stream>>>(U, kmaxp, v, out0, 6, 6);
  }

  // 7) attn = one-hot(kmax)
  onehot_kernel<<<dim3(2048), 256, 0, stream>>>(kmaxp, (f32x4*)attn,
                                                (int)((size_t)NB * NH * SEQ * SEQ / 4));
}